// Round 1
// baseline (718.051 us; speedup 1.0000x reference)
//
#include <hip/hip_runtime.h>
#include <math.h>

#define HCDIM 256   // H*C
#define HEADS 8
#define CH 32
#define NEG 0.2f

__device__ __forceinline__ float4 ld4(const float* p){ return *reinterpret_cast<const float4*>(p); }
__device__ __forceinline__ void st4(float* p, float a, float b, float c, float d){
    float4 v; v.x=a; v.y=b; v.z=c; v.w=d; *reinterpret_cast<float4*>(p)=v;
}

// ---------- preprocessing ----------
__global__ void k_init(int* deg, float* lsum, int* cursor, int n){
    int i = blockIdx.x*blockDim.x + threadIdx.x;
    if (i < n){ deg[i]=0; lsum[i]=0.f; cursor[i]=0; }
}

__global__ void k_count(const int* __restrict__ dst, const float* __restrict__ eattr,
                        int* deg, float* lsum, int E){
    int e = blockIdx.x*blockDim.x + threadIdx.x;
    if (e < E){
        int d = dst[e];
        atomicAdd(&deg[d], 1);
        atomicAdd(&lsum[d], eattr[e]);
    }
}

// single-block scan: offs[0]=0, offs[i+1]=sum deg[0..i]
__global__ void k_scan(const int* __restrict__ deg, int* __restrict__ offs, int n){
    __shared__ int wsum[16];
    __shared__ int carry;
    int tid = threadIdx.x;            // 1024 threads
    if (tid == 0) carry = 0;
    __syncthreads();
    int lane = tid & 63, wid = tid >> 6;
    for (int base = 0; base < n; base += 1024){
        int i = base + tid;
        int x = (i < n) ? deg[i] : 0;
        #pragma unroll
        for (int o = 1; o < 64; o <<= 1){
            int y = __shfl_up(x, o);
            if (lane >= o) x += y;
        }
        if (lane == 63) wsum[wid] = x;
        __syncthreads();
        if (tid == 0){
            int run = 0;
            for (int w = 0; w < 16; w++){ run += wsum[w]; wsum[w] = run; }
        }
        __syncthreads();
        int pre = (wid > 0 ? wsum[wid-1] : 0) + carry;
        int incl = x + pre;
        if (i < n) offs[i+1] = incl;
        __syncthreads();
        if (tid == 1023) carry = incl;
        __syncthreads();
    }
    if (tid == 0) offs[0] = 0;
}

__global__ void k_loopattr(const int* deg, const float* lsum, float* lattr, int n){
    int i = blockIdx.x*blockDim.x + threadIdx.x;
    if (i < n) lattr[i] = lsum[i] / fmaxf((float)deg[i], 1.0f);
}

__global__ void k_scatter(const int* __restrict__ src, const int* __restrict__ dst,
                          const float* __restrict__ eattr, const int* __restrict__ offs,
                          int* cursor, int* csr_src, float* csr_attr, int E){
    int e = blockIdx.x*blockDim.x + threadIdx.x;
    if (e < E){
        int d = dst[e];
        int pos = offs[d] + atomicAdd(&cursor[d], 1);
        csr_src[pos] = src[e];
        csr_attr[pos] = eattr[e];
    }
}

// ---------- dual GEMM: xl = h@Wl+bl ; xr = h@Wr+br  (dout = 256) ----------
__global__ __launch_bounds__(256) void k_dualgemm(
        const float* __restrict__ h, int din,
        const float* __restrict__ Wl, const float* __restrict__ bl,
        const float* __restrict__ Wr, const float* __restrict__ br,
        float* __restrict__ xl, float* __restrict__ xr, int n)
{
    const int ROWS = 16;
    __shared__ float hs[ROWS * HCDIM];   // stride = din (<=256)
    int row0 = blockIdx.x * ROWS;
    int j = threadIdx.x;                 // output column 0..255

    for (int idx = threadIdx.x; idx < ROWS*din; idx += 256){
        int r = idx / din, k = idx - r*din;
        int row = row0 + r;
        hs[r*din + k] = (row < n) ? h[(size_t)row*din + k] : 0.f;
    }
    __syncthreads();

    float accl[ROWS], accr[ROWS];
    float blj = bl[j], brj = br[j];
    #pragma unroll
    for (int r = 0; r < ROWS; r++){ accl[r] = blj; accr[r] = brj; }

    int k4 = din & ~3;
    for (int k = 0; k < k4; k += 4){
        float wl0 = Wl[(k+0)*HCDIM + j], wl1 = Wl[(k+1)*HCDIM + j];
        float wl2 = Wl[(k+2)*HCDIM + j], wl3 = Wl[(k+3)*HCDIM + j];
        float wr0 = Wr[(k+0)*HCDIM + j], wr1 = Wr[(k+1)*HCDIM + j];
        float wr2 = Wr[(k+2)*HCDIM + j], wr3 = Wr[(k+3)*HCDIM + j];
        #pragma unroll
        for (int r = 0; r < ROWS; r++){
            float4 hv = *reinterpret_cast<const float4*>(&hs[r*din + k]);
            accl[r] += hv.x*wl0 + hv.y*wl1 + hv.z*wl2 + hv.w*wl3;
            accr[r] += hv.x*wr0 + hv.y*wr1 + hv.z*wr2 + hv.w*wr3;
        }
    }
    for (int k = k4; k < din; k++){
        float wl = Wl[k*HCDIM + j], wr = Wr[k*HCDIM + j];
        #pragma unroll
        for (int r = 0; r < ROWS; r++){
            float hv = hs[r*din + k];
            accl[r] += hv*wl;
            accr[r] += hv*wr;
        }
    }
    #pragma unroll
    for (int r = 0; r < ROWS; r++){
        int row = row0 + r;
        if (row < n){
            xl[(size_t)row*HCDIM + j] = accl[r];
            xr[(size_t)row*HCDIM + j] = accr[r];
        }
    }
}

// ---------- fused GATv2 edge kernel: one wave per dst node ----------
__global__ __launch_bounds__(256) void k_gat(
        const float* __restrict__ xl, const float* __restrict__ xr,
        const int* __restrict__ csr_src, const float* __restrict__ csr_attr,
        const int* __restrict__ offs, const float* __restrict__ lattr,
        const float* __restrict__ We, const float* __restrict__ att,
        const float* __restrict__ bias, float* __restrict__ hout,
        int n, int concat)
{
    int wid = threadIdx.x >> 6;
    int lane = threadIdx.x & 63;
    int v = blockIdx.x*4 + wid;
    if (v >= n) return;
    const int cb = lane*4;               // channel base: head=lane/8, ch=(lane%8)*4
    float4 We4  = ld4(We + cb);
    float4 att4 = ld4(att + cb);
    float4 xr4  = ld4(xr + (size_t)v*HCDIM + cb);

    float mh = -INFINITY, s = 0.f;
    float ax = 0.f, ay = 0.f, az = 0.f, aw = 0.f;
    int pbeg = offs[v], pend = offs[v+1];

    for (int p = pbeg - 1; p < pend; ++p){
        int u; float ea;
        if (p < pbeg){ u = v; ea = lattr[v]; }          // self loop
        else         { u = csr_src[p]; ea = csr_attr[p]; }
        float4 xu = ld4(xl + (size_t)u*HCDIM + cb);
        float tx = xu.x + xr4.x + ea*We4.x;
        float ty = xu.y + xr4.y + ea*We4.y;
        float tz = xu.z + xr4.z + ea*We4.z;
        float tw = xu.w + xr4.w + ea*We4.w;
        tx = tx > 0.f ? tx : NEG*tx;
        ty = ty > 0.f ? ty : NEG*ty;
        tz = tz > 0.f ? tz : NEG*tz;
        tw = tw > 0.f ? tw : NEG*tw;
        float part = tx*att4.x + ty*att4.y + tz*att4.z + tw*att4.w;
        part += __shfl_xor(part, 1);
        part += __shfl_xor(part, 2);
        part += __shfl_xor(part, 4);     // logit broadcast to head's 8 lanes
        float nm = fmaxf(mh, part);
        float sc = __expf(mh - nm);      // exp(-inf)=0 on first edge
        float w  = __expf(part - nm);
        s  = s*sc + w;
        ax = ax*sc + w*xu.x;
        ay = ay*sc + w*xu.y;
        az = az*sc + w*xu.z;
        aw = aw*sc + w*xu.w;
        mh = nm;
    }
    float inv = 1.f / s;
    if (concat){
        float4 b4 = ld4(bias + cb);
        st4(hout + (size_t)v*HCDIM + cb,
            fmaxf(ax*inv + b4.x, 0.f), fmaxf(ay*inv + b4.y, 0.f),
            fmaxf(az*inv + b4.z, 0.f), fmaxf(aw*inv + b4.w, 0.f));
    } else {
        float ox = ax*inv, oy = ay*inv, oz = az*inv, ow = aw*inv;
        #pragma unroll
        for (int o = 8; o < 64; o <<= 1){
            ox += __shfl_xor(ox, o); oy += __shfl_xor(oy, o);
            oz += __shfl_xor(oz, o); ow += __shfl_xor(ow, o);
        }
        int c0 = (lane & 7)*4;
        float4 b4 = ld4(bias + c0);
        ox = fmaxf(ox*0.125f + b4.x, 0.f);
        oy = fmaxf(oy*0.125f + b4.y, 0.f);
        oz = fmaxf(oz*0.125f + b4.z, 0.f);
        ow = fmaxf(ow*0.125f + b4.w, 0.f);
        if (lane < 8) st4(hout + (size_t)v*CH + c0, ox, oy, oz, ow);
    }
}

// ---------- MLP heads: 32 threads per item, log_softmax over 2 classes ----------
__global__ __launch_bounds__(256) void k_head(
        const float* __restrict__ hf,
        const int* __restrict__ src, const int* __restrict__ dst,
        const float* __restrict__ W1, const float* __restrict__ b1,
        const float* __restrict__ W2, const float* __restrict__ b2,
        float* __restrict__ out, int count, int is_edge)
{
    __shared__ float sh[8][CH];
    int g = threadIdx.x >> 5;
    int t = threadIdx.x & 31;
    int i = blockIdx.x*8 + g;
    float hv = 0.f;
    if (i < count){
        if (is_edge){
            int s = src[i], d = dst[i];
            hv = hf[(size_t)s*CH + t] + hf[(size_t)d*CH + t];
        } else {
            hv = hf[(size_t)i*CH + t];
        }
    }
    sh[g][t] = hv;
    __syncthreads();
    float z = b1[t];
    #pragma unroll
    for (int k = 0; k < CH; k++) z += sh[g][k] * W1[k*CH + t];
    z = fmaxf(z, 0.f);
    float r0 = z * W2[t*2 + 0];
    float r1 = z * W2[t*2 + 1];
    #pragma unroll
    for (int o = 1; o < 32; o <<= 1){
        r0 += __shfl_xor(r0, o);
        r1 += __shfl_xor(r1, o);
    }
    if (t == 0 && i < count){
        float z0 = r0 + b2[0], z1 = r1 + b2[1];
        float mm = fmaxf(z0, z1);
        float lse = mm + __logf(__expf(z0 - mm) + __expf(z1 - mm));
        out[(size_t)i*2 + 0] = z0 - lse;
        out[(size_t)i*2 + 1] = z1 - lse;
    }
}

extern "C" void kernel_launch(void* const* d_in, const int* in_sizes, int n_in,
                              void* d_out, int out_size, void* d_ws, size_t ws_size,
                              hipStream_t stream)
{
    const float* x     = (const float*)d_in[0];
    const int*   ei    = (const int*)d_in[1];
    const float* eattr = (const float*)d_in[2];
    int N = in_sizes[0] / 3;
    int E = in_sizes[2];
    const int* src0 = ei;
    const int* dst0 = ei + E;

    const float *Wl[3], *bl[3], *Wr[3], *br[3], *We[3], *att[3], *bias[3];
    for (int l = 0; l < 3; l++){
        int b = 3 + l*7;
        Wl[l]   = (const float*)d_in[b+0];
        bl[l]   = (const float*)d_in[b+1];
        Wr[l]   = (const float*)d_in[b+2];
        br[l]   = (const float*)d_in[b+3];
        We[l]   = (const float*)d_in[b+4];
        att[l]  = (const float*)d_in[b+5];
        bias[l] = (const float*)d_in[b+6];
    }
    const float* nhW1 = (const float*)d_in[24];
    const float* nhb1 = (const float*)d_in[25];
    const float* nhW2 = (const float*)d_in[26];
    const float* nhb2 = (const float*)d_in[27];
    const float* ehW1 = (const float*)d_in[28];
    const float* ehb1 = (const float*)d_in[29];
    const float* ehW2 = (const float*)d_in[30];
    const float* ehb2 = (const float*)d_in[31];

    char* ws = (char*)d_ws;
    auto alloc = [&](size_t bytes) -> char* {
        char* p = ws;
        ws += (bytes + 255) & ~(size_t)255;
        return p;
    };
    float* H0       = (float*)alloc((size_t)N*HCDIM*4);
    float* XL       = (float*)alloc((size_t)N*HCDIM*4);
    float* XR       = (float*)alloc((size_t)N*HCDIM*4);
    int*   deg      = (int*)alloc((size_t)N*4);
    float* lsum     = (float*)alloc((size_t)N*4);
    float* lattr    = (float*)alloc((size_t)N*4);
    int*   offs     = (int*)alloc((size_t)(N+1)*4);
    int*   cursor   = (int*)alloc((size_t)N*4);
    int*   csr_src  = (int*)alloc((size_t)E*4);
    float* csr_attr = (float*)alloc((size_t)E*4);

    // preprocessing
    k_init<<<(N+255)/256, 256, 0, stream>>>(deg, lsum, cursor, N);
    k_count<<<(E+255)/256, 256, 0, stream>>>(dst0, eattr, deg, lsum, E);
    k_scan<<<1, 1024, 0, stream>>>(deg, offs, N);
    k_loopattr<<<(N+255)/256, 256, 0, stream>>>(deg, lsum, lattr, N);
    k_scatter<<<(E+255)/256, 256, 0, stream>>>(src0, dst0, eattr, offs, cursor,
                                               csr_src, csr_attr, E);

    int gemm_grid = (N + 15) / 16;
    int gat_grid  = (N + 3) / 4;

    // layer 0 (din=3, input = x)
    k_dualgemm<<<gemm_grid, 256, 0, stream>>>(x, 3, Wl[0], bl[0], Wr[0], br[0], XL, XR, N);
    k_gat<<<gat_grid, 256, 0, stream>>>(XL, XR, csr_src, csr_attr, offs, lattr,
                                        We[0], att[0], bias[0], H0, N, 1);
    // layer 1 (din=256)
    k_dualgemm<<<gemm_grid, 256, 0, stream>>>(H0, HCDIM, Wl[1], bl[1], Wr[1], br[1], XL, XR, N);
    k_gat<<<gat_grid, 256, 0, stream>>>(XL, XR, csr_src, csr_attr, offs, lattr,
                                        We[1], att[1], bias[1], H0, N, 1);
    // layer 2 (din=256, concat=false -> writes N x 32 into H0)
    k_dualgemm<<<gemm_grid, 256, 0, stream>>>(H0, HCDIM, Wl[2], bl[2], Wr[2], br[2], XL, XR, N);
    k_gat<<<gat_grid, 256, 0, stream>>>(XL, XR, csr_src, csr_attr, offs, lattr,
                                        We[2], att[2], bias[2], H0, N, 0);

    // heads
    float* out_node = (float*)d_out;
    float* out_edge = out_node + (size_t)N*2;
    k_head<<<(N+7)/8, 256, 0, stream>>>(H0, nullptr, nullptr,
                                        nhW1, nhb1, nhW2, nhb2, out_node, N, 0);
    k_head<<<(E+7)/8, 256, 0, stream>>>(H0, src0, dst0,
                                        ehW1, ehb1, ehW2, ehb2, out_edge, E, 1);
}

// Round 2
// 490.255 us; speedup vs baseline: 1.4646x; 1.4646x over previous
//
#include <hip/hip_runtime.h>
#include <math.h>

#define HCDIM 256   // H*C
#define HEADS 8
#define CH 32
#define NEG 0.2f

__device__ __forceinline__ float4 ld4(const float* p){ return *reinterpret_cast<const float4*>(p); }
__device__ __forceinline__ void st4(float* p, float a, float b, float c, float d){
    float4 v; v.x=a; v.y=b; v.z=c; v.w=d; *reinterpret_cast<float4*>(p)=v;
}
__device__ __forceinline__ unsigned short f2bf(float f){
    union { float f; unsigned u; } x; x.f = f;
    unsigned r = x.u + 0x7fff + ((x.u >> 16) & 1);   // RNE
    return (unsigned short)(r >> 16);
}

// ---------- preprocessing ----------
__global__ void k_init(int* deg, float* lsum, int* cursor, int n){
    int i = blockIdx.x*blockDim.x + threadIdx.x;
    if (i < n){ deg[i]=0; lsum[i]=0.f; cursor[i]=0; }
}

__global__ void k_count(const int* __restrict__ dst, const float* __restrict__ eattr,
                        int* deg, float* lsum, int E){
    int e = blockIdx.x*blockDim.x + threadIdx.x;
    if (e < E){
        int d = dst[e];
        atomicAdd(&deg[d], 1);
        atomicAdd(&lsum[d], eattr[e]);
    }
}

// single-block scan: offs[0]=0, offs[i+1]=sum deg[0..i]
__global__ void k_scan(const int* __restrict__ deg, int* __restrict__ offs, int n){
    __shared__ int wsum[16];
    __shared__ int carry;
    int tid = threadIdx.x;            // 1024 threads
    if (tid == 0) carry = 0;
    __syncthreads();
    int lane = tid & 63, wid = tid >> 6;
    for (int base = 0; base < n; base += 1024){
        int i = base + tid;
        int x = (i < n) ? deg[i] : 0;
        #pragma unroll
        for (int o = 1; o < 64; o <<= 1){
            int y = __shfl_up(x, o);
            if (lane >= o) x += y;
        }
        if (lane == 63) wsum[wid] = x;
        __syncthreads();
        if (tid == 0){
            int run = 0;
            for (int w = 0; w < 16; w++){ run += wsum[w]; wsum[w] = run; }
        }
        __syncthreads();
        int pre = (wid > 0 ? wsum[wid-1] : 0) + carry;
        int incl = x + pre;
        if (i < n) offs[i+1] = incl;
        __syncthreads();
        if (tid == 1023) carry = incl;
        __syncthreads();
    }
    if (tid == 0) offs[0] = 0;
}

__global__ void k_loopattr(const int* deg, const float* lsum, float* lattr, int n){
    int i = blockIdx.x*blockDim.x + threadIdx.x;
    if (i < n) lattr[i] = lsum[i] / fmaxf((float)deg[i], 1.0f);
}

__global__ void k_scatter(const int* __restrict__ src, const int* __restrict__ dst,
                          const float* __restrict__ eattr, const int* __restrict__ offs,
                          int* cursor, int* csr_src, float* csr_attr, int E){
    int e = blockIdx.x*blockDim.x + threadIdx.x;
    if (e < E){
        int d = dst[e];
        int pos = offs[d] + atomicAdd(&cursor[d], 1);
        csr_src[pos] = src[e];
        csr_attr[pos] = eattr[e];
    }
}

// ---------- fp32 dual GEMM (layer 0 only, din=3) ----------
__global__ __launch_bounds__(256) void k_dualgemm(
        const float* __restrict__ h, int din,
        const float* __restrict__ Wl, const float* __restrict__ bl,
        const float* __restrict__ Wr, const float* __restrict__ br,
        float* __restrict__ xl, float* __restrict__ xr, int n)
{
    const int ROWS = 16;
    __shared__ float hs[ROWS * HCDIM];
    int row0 = blockIdx.x * ROWS;
    int j = threadIdx.x;

    for (int idx = threadIdx.x; idx < ROWS*din; idx += 256){
        int r = idx / din, k = idx - r*din;
        int row = row0 + r;
        hs[r*din + k] = (row < n) ? h[(size_t)row*din + k] : 0.f;
    }
    __syncthreads();

    float accl[ROWS], accr[ROWS];
    float blj = bl[j], brj = br[j];
    #pragma unroll
    for (int r = 0; r < ROWS; r++){ accl[r] = blj; accr[r] = brj; }

    for (int k = 0; k < din; k++){
        float wl = Wl[k*HCDIM + j], wr = Wr[k*HCDIM + j];
        #pragma unroll
        for (int r = 0; r < ROWS; r++){
            float hv = hs[r*din + k];
            accl[r] += hv*wl;
            accr[r] += hv*wr;
        }
    }
    #pragma unroll
    for (int r = 0; r < ROWS; r++){
        int row = row0 + r;
        if (row < n){
            xl[(size_t)row*HCDIM + j] = accl[r];
            xr[(size_t)row*HCDIM + j] = accr[r];
        }
    }
}

// ---------- weight convert+transpose: Wt[n][k] = bf16(W{l,r}[k][n]) ----------
__global__ __launch_bounds__(256) void k_cvtw(const float* __restrict__ Wl,
                                              const float* __restrict__ Wr,
                                              unsigned short* __restrict__ Wt){
    int idx = blockIdx.x*256 + threadIdx.x;   // idx = nout*256 + k, nout in [0,512)
    int nout = idx >> 8, k = idx & 255;
    float v = (nout < 256) ? Wl[k*HCDIM + nout] : Wr[k*HCDIM + (nout - 256)];
    Wt[idx] = f2bf(v);
}

// ---------- bf16 MFMA GEMM: [xl | xr] = h @ [Wl | Wr] + [bl | br] ----------
// A = h [n][256] fp32 (converted to bf16 during staging); B = Wt [512][256] bf16 n-major
#define BM 128
#define BN 128
#define BK 32
#define LDK 40   // padded LDS stride (bf16 elems): 80B rows -> ~2-way bank conflicts only

typedef __attribute__((ext_vector_type(8))) short bf16x8;
typedef __attribute__((ext_vector_type(4))) float f32x4;

__global__ __launch_bounds__(256) void k_mfma_gemm(
        const float* __restrict__ h,
        const unsigned short* __restrict__ Wt,
        const float* __restrict__ bl, const float* __restrict__ br,
        float* __restrict__ xl, float* __restrict__ xr, int n)
{
    __shared__ unsigned short As[BM*LDK];
    __shared__ unsigned short Bs[BN*LDK];
    int tid = threadIdx.x;
    int row0 = blockIdx.x * BM;
    int col0 = blockIdx.y * BN;      // 0,128,256,384 over [Wl|Wr]

    int l = tid & 63, w = tid >> 6;
    int wm = (w >> 1) * 64, wn = (w & 1) * 64;

    f32x4 acc[4][4] = {};

    // staging map: 2 threads per row, 16 elems each
    int srow = tid >> 1;
    int skoff = (tid & 1) * 16;

    for (int kt = 0; kt < 8; ++kt){
        int kb = kt * BK;
        // A: 16 fp32 -> bf16
        float4 av0, av1, av2, av3;
        int grow = row0 + srow;
        if (grow < n){
            const float* ap = h + (size_t)grow*HCDIM + kb + skoff;
            av0 = ld4(ap); av1 = ld4(ap+4); av2 = ld4(ap+8); av3 = ld4(ap+12);
        } else {
            av0.x=av0.y=av0.z=av0.w=0.f; av1=av0; av2=av0; av3=av0;
        }
        // B: 16 bf16 (2x uint4)
        const uint4* bp = reinterpret_cast<const uint4*>(Wt + (size_t)(col0+srow)*HCDIM + kb + skoff);
        uint4 bv0 = bp[0], bv1 = bp[1];

        __syncthreads();   // previous iteration's LDS reads complete

        uint4 apk0, apk1;
        apk0.x = (unsigned)f2bf(av0.x) | ((unsigned)f2bf(av0.y) << 16);
        apk0.y = (unsigned)f2bf(av0.z) | ((unsigned)f2bf(av0.w) << 16);
        apk0.z = (unsigned)f2bf(av1.x) | ((unsigned)f2bf(av1.y) << 16);
        apk0.w = (unsigned)f2bf(av1.z) | ((unsigned)f2bf(av1.w) << 16);
        apk1.x = (unsigned)f2bf(av2.x) | ((unsigned)f2bf(av2.y) << 16);
        apk1.y = (unsigned)f2bf(av2.z) | ((unsigned)f2bf(av2.w) << 16);
        apk1.z = (unsigned)f2bf(av3.x) | ((unsigned)f2bf(av3.y) << 16);
        apk1.w = (unsigned)f2bf(av3.z) | ((unsigned)f2bf(av3.w) << 16);
        *reinterpret_cast<uint4*>(&As[srow*LDK + skoff])     = apk0;
        *reinterpret_cast<uint4*>(&As[srow*LDK + skoff + 8]) = apk1;
        *reinterpret_cast<uint4*>(&Bs[srow*LDK + skoff])     = bv0;
        *reinterpret_cast<uint4*>(&Bs[srow*LDK + skoff + 8]) = bv1;

        __syncthreads();

        bf16x8 af[4], bfr[4];
        #pragma unroll
        for (int m = 0; m < 4; m++)
            af[m] = *reinterpret_cast<const bf16x8*>(&As[(wm + m*16 + (l & 15))*LDK + ((l >> 4)*8)]);
        #pragma unroll
        for (int nn = 0; nn < 4; nn++)
            bfr[nn] = *reinterpret_cast<const bf16x8*>(&Bs[(wn + nn*16 + (l & 15))*LDK + ((l >> 4)*8)]);
        #pragma unroll
        for (int m = 0; m < 4; m++)
            #pragma unroll
            for (int nn = 0; nn < 4; nn++)
                acc[m][nn] = __builtin_amdgcn_mfma_f32_16x16x32_bf16(af[m], bfr[nn], acc[m][nn], 0, 0, 0);
    }

    // epilogue: bias + store (block-uniform xl/xr half)
    float* dstp; const float* biasp; int cbase;
    if (col0 < 256){ dstp = xl; biasp = bl; cbase = col0; }
    else           { dstp = xr; biasp = br; cbase = col0 - 256; }

    #pragma unroll
    for (int nn = 0; nn < 4; nn++){
        int gc = cbase + wn + nn*16 + (l & 15);
        float bb = biasp[gc];
        #pragma unroll
        for (int m = 0; m < 4; m++){
            int r0 = row0 + wm + m*16 + ((l >> 4) * 4);
            #pragma unroll
            for (int v = 0; v < 4; v++){
                int rr = r0 + v;
                if (rr < n) dstp[(size_t)rr*HCDIM + gc] = acc[m][nn][v] + bb;
            }
        }
    }
}

// ---------- fused GATv2 edge kernel: one wave per dst node ----------
__global__ __launch_bounds__(256) void k_gat(
        const float* __restrict__ xl, const float* __restrict__ xr,
        const int* __restrict__ csr_src, const float* __restrict__ csr_attr,
        const int* __restrict__ offs, const float* __restrict__ lattr,
        const float* __restrict__ We, const float* __restrict__ att,
        const float* __restrict__ bias, float* __restrict__ hout,
        int n, int concat)
{
    int wid = threadIdx.x >> 6;
    int lane = threadIdx.x & 63;
    int v = blockIdx.x*4 + wid;
    if (v >= n) return;
    const int cb = lane*4;               // head=lane/8, ch=(lane%8)*4
    float4 We4  = ld4(We + cb);
    float4 att4 = ld4(att + cb);
    float4 xr4  = ld4(xr + (size_t)v*HCDIM + cb);

    float mh = -INFINITY, s = 0.f;
    float ax = 0.f, ay = 0.f, az = 0.f, aw = 0.f;
    int pbeg = offs[v], pend = offs[v+1];

    for (int p = pbeg - 1; p < pend; ++p){
        int u; float ea;
        if (p < pbeg){ u = v; ea = lattr[v]; }          // self loop
        else         { u = csr_src[p]; ea = csr_attr[p]; }
        float4 xu = ld4(xl + (size_t)u*HCDIM + cb);
        float tx = xu.x + xr4.x + ea*We4.x;
        float ty = xu.y + xr4.y + ea*We4.y;
        float tz = xu.z + xr4.z + ea*We4.z;
        float tw = xu.w + xr4.w + ea*We4.w;
        tx = tx > 0.f ? tx : NEG*tx;
        ty = ty > 0.f ? ty : NEG*ty;
        tz = tz > 0.f ? tz : NEG*tz;
        tw = tw > 0.f ? tw : NEG*tw;
        float part = tx*att4.x + ty*att4.y + tz*att4.z + tw*att4.w;
        part += __shfl_xor(part, 1);
        part += __shfl_xor(part, 2);
        part += __shfl_xor(part, 4);     // logit broadcast within head's 8 lanes
        float nm = fmaxf(mh, part);
        float sc = __expf(mh - nm);
        float w  = __expf(part - nm);
        s  = s*sc + w;
        ax = ax*sc + w*xu.x;
        ay = ay*sc + w*xu.y;
        az = az*sc + w*xu.z;
        aw = aw*sc + w*xu.w;
        mh = nm;
    }
    float inv = 1.f / s;
    if (concat){
        float4 b4 = ld4(bias + cb);
        st4(hout + (size_t)v*HCDIM + cb,
            fmaxf(ax*inv + b4.x, 0.f), fmaxf(ay*inv + b4.y, 0.f),
            fmaxf(az*inv + b4.z, 0.f), fmaxf(aw*inv + b4.w, 0.f));
    } else {
        float ox = ax*inv, oy = ay*inv, oz = az*inv, ow = aw*inv;
        #pragma unroll
        for (int o = 8; o < 64; o <<= 1){
            ox += __shfl_xor(ox, o); oy += __shfl_xor(oy, o);
            oz += __shfl_xor(oz, o); ow += __shfl_xor(ow, o);
        }
        int c0 = (lane & 7)*4;
        float4 b4 = ld4(bias + c0);
        ox = fmaxf(ox*0.125f + b4.x, 0.f);
        oy = fmaxf(oy*0.125f + b4.y, 0.f);
        oz = fmaxf(oz*0.125f + b4.z, 0.f);
        ow = fmaxf(ow*0.125f + b4.w, 0.f);
        if (lane < 8) st4(hout + (size_t)v*CH + c0, ox, oy, oz, ow);
    }
}

// ---------- MLP heads ----------
__global__ __launch_bounds__(256) void k_head(
        const float* __restrict__ hf,
        const int* __restrict__ src, const int* __restrict__ dst,
        const float* __restrict__ W1, const float* __restrict__ b1,
        const float* __restrict__ W2, const float* __restrict__ b2,
        float* __restrict__ out, int count, int is_edge)
{
    __shared__ float sh[8][CH];
    int g = threadIdx.x >> 5;
    int t = threadIdx.x & 31;
    int i = blockIdx.x*8 + g;
    float hv = 0.f;
    if (i < count){
        if (is_edge){
            int s = src[i], d = dst[i];
            hv = hf[(size_t)s*CH + t] + hf[(size_t)d*CH + t];
        } else {
            hv = hf[(size_t)i*CH + t];
        }
    }
    sh[g][t] = hv;
    __syncthreads();
    float z = b1[t];
    #pragma unroll
    for (int k = 0; k < CH; k++) z += sh[g][k] * W1[k*CH + t];
    z = fmaxf(z, 0.f);
    float r0 = z * W2[t*2 + 0];
    float r1 = z * W2[t*2 + 1];
    #pragma unroll
    for (int o = 1; o < 32; o <<= 1){
        r0 += __shfl_xor(r0, o);
        r1 += __shfl_xor(r1, o);
    }
    if (t == 0 && i < count){
        float z0 = r0 + b2[0], z1 = r1 + b2[1];
        float mm = fmaxf(z0, z1);
        float lse = mm + __logf(__expf(z0 - mm) + __expf(z1 - mm));
        out[(size_t)i*2 + 0] = z0 - lse;
        out[(size_t)i*2 + 1] = z1 - lse;
    }
}

extern "C" void kernel_launch(void* const* d_in, const int* in_sizes, int n_in,
                              void* d_out, int out_size, void* d_ws, size_t ws_size,
                              hipStream_t stream)
{
    const float* x     = (const float*)d_in[0];
    const int*   ei    = (const int*)d_in[1];
    const float* eattr = (const float*)d_in[2];
    int N = in_sizes[0] / 3;
    int E = in_sizes[2];
    const int* src0 = ei;
    const int* dst0 = ei + E;

    const float *Wl[3], *bl[3], *Wr[3], *br[3], *We[3], *att[3], *bias[3];
    for (int l = 0; l < 3; l++){
        int b = 3 + l*7;
        Wl[l]   = (const float*)d_in[b+0];
        bl[l]   = (const float*)d_in[b+1];
        Wr[l]   = (const float*)d_in[b+2];
        br[l]   = (const float*)d_in[b+3];
        We[l]   = (const float*)d_in[b+4];
        att[l]  = (const float*)d_in[b+5];
        bias[l] = (const float*)d_in[b+6];
    }
    const float* nhW1 = (const float*)d_in[24];
    const float* nhb1 = (const float*)d_in[25];
    const float* nhW2 = (const float*)d_in[26];
    const float* nhb2 = (const float*)d_in[27];
    const float* ehW1 = (const float*)d_in[28];
    const float* ehb1 = (const float*)d_in[29];
    const float* ehW2 = (const float*)d_in[30];
    const float* ehb2 = (const float*)d_in[31];

    char* ws = (char*)d_ws;
    auto alloc = [&](size_t bytes) -> char* {
        char* p = ws;
        ws += (bytes + 255) & ~(size_t)255;
        return p;
    };
    float* H0       = (float*)alloc((size_t)N*HCDIM*4);
    float* XL       = (float*)alloc((size_t)N*HCDIM*4);
    float* XR       = (float*)alloc((size_t)N*HCDIM*4);
    int*   deg      = (int*)alloc((size_t)N*4);
    float* lsum     = (float*)alloc((size_t)N*4);
    float* lattr    = (float*)alloc((size_t)N*4);
    int*   offs     = (int*)alloc((size_t)(N+1)*4);
    int*   cursor   = (int*)alloc((size_t)N*4);
    int*   csr_src  = (int*)alloc((size_t)E*4);
    float* csr_attr = (float*)alloc((size_t)E*4);
    unsigned short* Wt = (unsigned short*)alloc((size_t)512*HCDIM*2);

    // preprocessing
    k_init<<<(N+255)/256, 256, 0, stream>>>(deg, lsum, cursor, N);
    k_count<<<(E+255)/256, 256, 0, stream>>>(dst0, eattr, deg, lsum, E);
    k_scan<<<1, 1024, 0, stream>>>(deg, offs, N);
    k_loopattr<<<(N+255)/256, 256, 0, stream>>>(deg, lsum, lattr, N);
    k_scatter<<<(E+255)/256, 256, 0, stream>>>(src0, dst0, eattr, offs, cursor,
                                               csr_src, csr_attr, E);

    int gat_grid  = (N + 3) / 4;
    dim3 mfma_grid((N + BM - 1) / BM, 4);

    // layer 0 (din=3, fp32 vector GEMM)
    k_dualgemm<<<(N+15)/16, 256, 0, stream>>>(x, 3, Wl[0], bl[0], Wr[0], br[0], XL, XR, N);
    k_gat<<<gat_grid, 256, 0, stream>>>(XL, XR, csr_src, csr_attr, offs, lattr,
                                        We[0], att[0], bias[0], H0, N, 1);
    // layer 1 (din=256, bf16 MFMA)
    k_cvtw<<<512, 256, 0, stream>>>(Wl[1], Wr[1], Wt);
    k_mfma_gemm<<<mfma_grid, 256, 0, stream>>>(H0, Wt, bl[1], br[1], XL, XR, N);
    k_gat<<<gat_grid, 256, 0, stream>>>(XL, XR, csr_src, csr_attr, offs, lattr,
                                        We[1], att[1], bias[1], H0, N, 1);
    // layer 2 (din=256, bf16 MFMA, concat=false)
    k_cvtw<<<512, 256, 0, stream>>>(Wl[2], Wr[2], Wt);
    k_mfma_gemm<<<mfma_grid, 256, 0, stream>>>(H0, Wt, bl[2], br[2], XL, XR, N);
    k_gat<<<gat_grid, 256, 0, stream>>>(XL, XR, csr_src, csr_attr, offs, lattr,
                                        We[2], att[2], bias[2], H0, N, 0);

    // heads
    float* out_node = (float*)d_out;
    float* out_edge = out_node + (size_t)N*2;
    k_head<<<(N+7)/8, 256, 0, stream>>>(H0, nullptr, nullptr,
                                        nhW1, nhb1, nhW2, nhb2, out_node, N, 0);
    k_head<<<(E+7)/8, 256, 0, stream>>>(H0, src0, dst0,
                                        ehW1, ehb1, ehW2, ehb2, out_edge, E, 1);
}

// Round 3
// 436.365 us; speedup vs baseline: 1.6455x; 1.1235x over previous
//
#include <hip/hip_runtime.h>
#include <math.h>

#define HCDIM 256   // H*C
#define HEADS 8
#define CH 32
#define NEG 0.2f

__device__ __forceinline__ float4 ld4(const float* p){ return *reinterpret_cast<const float4*>(p); }
__device__ __forceinline__ void st4(float* p, float a, float b, float c, float d){
    float4 v; v.x=a; v.y=b; v.z=c; v.w=d; *reinterpret_cast<float4*>(p)=v;
}
__device__ __forceinline__ unsigned short f2bf(float f){
    union { float f; unsigned u; } x; x.f = f;
    unsigned r = x.u + 0x7fff + ((x.u >> 16) & 1);   // RNE
    return (unsigned short)(r >> 16);
}

// ---------- preprocessing ----------
__global__ void k_init(int* deg, float* lsum, int* cursor, int n){
    int i = blockIdx.x*blockDim.x + threadIdx.x;
    if (i < n){ deg[i]=0; lsum[i]=0.f; cursor[i]=0; }
}

__global__ void k_count(const int* __restrict__ dst, const float* __restrict__ eattr,
                        int* deg, float* lsum, int E){
    int e = blockIdx.x*blockDim.x + threadIdx.x;
    if (e < E){
        int d = dst[e];
        atomicAdd(&deg[d], 1);
        atomicAdd(&lsum[d], eattr[e]);
    }
}

// single-block scan: offs[0]=0, offs[i+1]=sum deg[0..i]
__global__ void k_scan(const int* __restrict__ deg, int* __restrict__ offs, int n){
    __shared__ int wsum[16];
    __shared__ int carry;
    int tid = threadIdx.x;            // 1024 threads
    if (tid == 0) carry = 0;
    __syncthreads();
    int lane = tid & 63, wid = tid >> 6;
    for (int base = 0; base < n; base += 1024){
        int i = base + tid;
        int x = (i < n) ? deg[i] : 0;
        #pragma unroll
        for (int o = 1; o < 64; o <<= 1){
            int y = __shfl_up(x, o);
            if (lane >= o) x += y;
        }
        if (lane == 63) wsum[wid] = x;
        __syncthreads();
        if (tid == 0){
            int run = 0;
            for (int w = 0; w < 16; w++){ run += wsum[w]; wsum[w] = run; }
        }
        __syncthreads();
        int pre = (wid > 0 ? wsum[wid-1] : 0) + carry;
        int incl = x + pre;
        if (i < n) offs[i+1] = incl;
        __syncthreads();
        if (tid == 1023) carry = incl;
        __syncthreads();
    }
    if (tid == 0) offs[0] = 0;
}

__global__ void k_loopattr(const int* deg, const float* lsum, float* lattr, int n){
    int i = blockIdx.x*blockDim.x + threadIdx.x;
    if (i < n) lattr[i] = lsum[i] / fmaxf((float)deg[i], 1.0f);
}

__global__ void k_scatter(const int* __restrict__ src, const int* __restrict__ dst,
                          const float* __restrict__ eattr, const int* __restrict__ offs,
                          int* cursor, int* csr_src, float* csr_attr, int E){
    int e = blockIdx.x*blockDim.x + threadIdx.x;
    if (e < E){
        int d = dst[e];
        int pos = offs[d] + atomicAdd(&cursor[d], 1);
        csr_src[pos] = src[e];
        csr_attr[pos] = eattr[e];
    }
}

// ---------- fp32 dual GEMM (layer 0 only, din=3) ----------
__global__ __launch_bounds__(256) void k_dualgemm(
        const float* __restrict__ h, int din,
        const float* __restrict__ Wl, const float* __restrict__ bl,
        const float* __restrict__ Wr, const float* __restrict__ br,
        float* __restrict__ xl, float* __restrict__ xr, int n)
{
    const int ROWS = 16;
    __shared__ float hs[ROWS * HCDIM];
    int row0 = blockIdx.x * ROWS;
    int j = threadIdx.x;

    for (int idx = threadIdx.x; idx < ROWS*din; idx += 256){
        int r = idx / din, k = idx - r*din;
        int row = row0 + r;
        hs[r*din + k] = (row < n) ? h[(size_t)row*din + k] : 0.f;
    }
    __syncthreads();

    float accl[ROWS], accr[ROWS];
    float blj = bl[j], brj = br[j];
    #pragma unroll
    for (int r = 0; r < ROWS; r++){ accl[r] = blj; accr[r] = brj; }

    for (int k = 0; k < din; k++){
        float wl = Wl[k*HCDIM + j], wr = Wr[k*HCDIM + j];
        #pragma unroll
        for (int r = 0; r < ROWS; r++){
            float hv = hs[r*din + k];
            accl[r] += hv*wl;
            accr[r] += hv*wr;
        }
    }
    #pragma unroll
    for (int r = 0; r < ROWS; r++){
        int row = row0 + r;
        if (row < n){
            xl[(size_t)row*HCDIM + j] = accl[r];
            xr[(size_t)row*HCDIM + j] = accr[r];
        }
    }
}

// ---------- weight convert+transpose: Wt[n][k] = bf16(W{l,r}[k][n]) ----------
__global__ __launch_bounds__(256) void k_cvtw(const float* __restrict__ Wl,
                                              const float* __restrict__ Wr,
                                              unsigned short* __restrict__ Wt){
    int idx = blockIdx.x*256 + threadIdx.x;   // idx = nout*256 + k, nout in [0,512)
    int nout = idx >> 8, k = idx & 255;
    float v = (nout < 256) ? Wl[k*HCDIM + nout] : Wr[k*HCDIM + (nout - 256)];
    Wt[idx] = f2bf(v);
}

// ---------- bf16 MFMA GEMM: [xl | xr] = h @ [Wl | Wr] + [bl | br] ----------
#define BM 128
#define BN 128
#define BK 32
#define LDK 40   // padded LDS stride (bf16 elems)

typedef __attribute__((ext_vector_type(8))) short bf16x8;
typedef __attribute__((ext_vector_type(4))) float f32x4;

__global__ __launch_bounds__(256) void k_mfma_gemm(
        const float* __restrict__ h,
        const unsigned short* __restrict__ Wt,
        const float* __restrict__ bl, const float* __restrict__ br,
        float* __restrict__ xl, float* __restrict__ xr, int n)
{
    __shared__ unsigned short As[BM*LDK];
    __shared__ unsigned short Bs[BN*LDK];
    int tid = threadIdx.x;
    int row0 = blockIdx.x * BM;
    int col0 = blockIdx.y * BN;      // 0,128,256,384 over [Wl|Wr]

    int l = tid & 63, w = tid >> 6;
    int wm = (w >> 1) * 64, wn = (w & 1) * 64;

    f32x4 acc[4][4] = {};

    int srow = tid >> 1;
    int skoff = (tid & 1) * 16;

    for (int kt = 0; kt < 8; ++kt){
        int kb = kt * BK;
        float4 av0, av1, av2, av3;
        int grow = row0 + srow;
        if (grow < n){
            const float* ap = h + (size_t)grow*HCDIM + kb + skoff;
            av0 = ld4(ap); av1 = ld4(ap+4); av2 = ld4(ap+8); av3 = ld4(ap+12);
        } else {
            av0.x=av0.y=av0.z=av0.w=0.f; av1=av0; av2=av0; av3=av0;
        }
        const uint4* bp = reinterpret_cast<const uint4*>(Wt + (size_t)(col0+srow)*HCDIM + kb + skoff);
        uint4 bv0 = bp[0], bv1 = bp[1];

        __syncthreads();

        uint4 apk0, apk1;
        apk0.x = (unsigned)f2bf(av0.x) | ((unsigned)f2bf(av0.y) << 16);
        apk0.y = (unsigned)f2bf(av0.z) | ((unsigned)f2bf(av0.w) << 16);
        apk0.z = (unsigned)f2bf(av1.x) | ((unsigned)f2bf(av1.y) << 16);
        apk0.w = (unsigned)f2bf(av1.z) | ((unsigned)f2bf(av1.w) << 16);
        apk1.x = (unsigned)f2bf(av2.x) | ((unsigned)f2bf(av2.y) << 16);
        apk1.y = (unsigned)f2bf(av2.z) | ((unsigned)f2bf(av2.w) << 16);
        apk1.z = (unsigned)f2bf(av3.x) | ((unsigned)f2bf(av3.y) << 16);
        apk1.w = (unsigned)f2bf(av3.z) | ((unsigned)f2bf(av3.w) << 16);
        *reinterpret_cast<uint4*>(&As[srow*LDK + skoff])     = apk0;
        *reinterpret_cast<uint4*>(&As[srow*LDK + skoff + 8]) = apk1;
        *reinterpret_cast<uint4*>(&Bs[srow*LDK + skoff])     = bv0;
        *reinterpret_cast<uint4*>(&Bs[srow*LDK + skoff + 8]) = bv1;

        __syncthreads();

        bf16x8 af[4], bfr[4];
        #pragma unroll
        for (int m = 0; m < 4; m++)
            af[m] = *reinterpret_cast<const bf16x8*>(&As[(wm + m*16 + (l & 15))*LDK + ((l >> 4)*8)]);
        #pragma unroll
        for (int nn = 0; nn < 4; nn++)
            bfr[nn] = *reinterpret_cast<const bf16x8*>(&Bs[(wn + nn*16 + (l & 15))*LDK + ((l >> 4)*8)]);
        #pragma unroll
        for (int m = 0; m < 4; m++)
            #pragma unroll
            for (int nn = 0; nn < 4; nn++)
                acc[m][nn] = __builtin_amdgcn_mfma_f32_16x16x32_bf16(af[m], bfr[nn], acc[m][nn], 0, 0, 0);
    }

    float* dstp; const float* biasp; int cbase;
    if (col0 < 256){ dstp = xl; biasp = bl; cbase = col0; }
    else           { dstp = xr; biasp = br; cbase = col0 - 256; }

    #pragma unroll
    for (int nn = 0; nn < 4; nn++){
        int gc = cbase + wn + nn*16 + (l & 15);
        float bb = biasp[gc];
        #pragma unroll
        for (int m = 0; m < 4; m++){
            int r0 = row0 + wm + m*16 + ((l >> 4) * 4);
            #pragma unroll
            for (int v = 0; v < 4; v++){
                int rr = r0 + v;
                if (rr < n) dstp[(size_t)rr*HCDIM + gc] = acc[m][nn][v] + bb;
            }
        }
    }
}

// ---------- fused GATv2 edge kernel: one wave per dst node ----------
__global__ __launch_bounds__(256) void k_gat(
        const float* __restrict__ xl, const float* __restrict__ xr,
        const int* __restrict__ csr_src, const float* __restrict__ csr_attr,
        const int* __restrict__ offs, const float* __restrict__ lattr,
        const float* __restrict__ We, const float* __restrict__ att,
        const float* __restrict__ bias, float* __restrict__ hout,
        int n, int concat)
{
    int wid = threadIdx.x >> 6;
    int lane = threadIdx.x & 63;
    int v = blockIdx.x*4 + wid;
    if (v >= n) return;
    const int cb = lane*4;               // head=lane/8, ch=(lane%8)*4
    float4 We4  = ld4(We + cb);
    float4 att4 = ld4(att + cb);
    float4 xr4  = ld4(xr + (size_t)v*HCDIM + cb);

    float mh = -INFINITY, s = 0.f;
    float ax = 0.f, ay = 0.f, az = 0.f, aw = 0.f;
    int pbeg = offs[v], pend = offs[v+1];

    for (int p = pbeg - 1; p < pend; ++p){
        int u; float ea;
        if (p < pbeg){ u = v; ea = lattr[v]; }          // self loop
        else         { u = csr_src[p]; ea = csr_attr[p]; }
        float4 xu = ld4(xl + (size_t)u*HCDIM + cb);
        float tx = xu.x + xr4.x + ea*We4.x;
        float ty = xu.y + xr4.y + ea*We4.y;
        float tz = xu.z + xr4.z + ea*We4.z;
        float tw = xu.w + xr4.w + ea*We4.w;
        tx = tx > 0.f ? tx : NEG*tx;
        ty = ty > 0.f ? ty : NEG*ty;
        tz = tz > 0.f ? tz : NEG*tz;
        tw = tw > 0.f ? tw : NEG*tw;
        float part = tx*att4.x + ty*att4.y + tz*att4.z + tw*att4.w;
        part += __shfl_xor(part, 1);
        part += __shfl_xor(part, 2);
        part += __shfl_xor(part, 4);     // logit broadcast within head's 8 lanes
        float nm = fmaxf(mh, part);
        float sc = __expf(mh - nm);
        float w  = __expf(part - nm);
        s  = s*sc + w;
        ax = ax*sc + w*xu.x;
        ay = ay*sc + w*xu.y;
        az = az*sc + w*xu.z;
        aw = aw*sc + w*xu.w;
        mh = nm;
    }
    float inv = 1.f / s;
    if (concat){
        float4 b4 = ld4(bias + cb);
        st4(hout + (size_t)v*HCDIM + cb,
            fmaxf(ax*inv + b4.x, 0.f), fmaxf(ay*inv + b4.y, 0.f),
            fmaxf(az*inv + b4.z, 0.f), fmaxf(aw*inv + b4.w, 0.f));
    } else {
        float ox = ax*inv, oy = ay*inv, oz = az*inv, ow = aw*inv;
        #pragma unroll
        for (int o = 8; o < 64; o <<= 1){
            ox += __shfl_xor(ox, o); oy += __shfl_xor(oy, o);
            oz += __shfl_xor(oz, o); ow += __shfl_xor(ow, o);
        }
        int c0 = (lane & 7)*4;
        float4 b4 = ld4(bias + c0);
        ox = fmaxf(ox*0.125f + b4.x, 0.f);
        oy = fmaxf(oy*0.125f + b4.y, 0.f);
        oz = fmaxf(oz*0.125f + b4.z, 0.f);
        ow = fmaxf(ow*0.125f + b4.w, 0.f);
        if (lane < 8) st4(hout + (size_t)v*CH + c0, ox, oy, oz, ow);
    }
}

// ---------- node head: 32 threads per node (N only — cheap) ----------
__global__ __launch_bounds__(256) void k_head(
        const float* __restrict__ hf,
        const float* __restrict__ W1, const float* __restrict__ b1,
        const float* __restrict__ W2, const float* __restrict__ b2,
        float* __restrict__ out, int count)
{
    __shared__ float sh[8][CH];
    int g = threadIdx.x >> 5;
    int t = threadIdx.x & 31;
    int i = blockIdx.x*8 + g;
    float hv = (i < count) ? hf[(size_t)i*CH + t] : 0.f;
    sh[g][t] = hv;
    __syncthreads();
    float z = b1[t];
    #pragma unroll
    for (int k = 0; k < CH; k++) z += sh[g][k] * W1[k*CH + t];
    z = fmaxf(z, 0.f);
    float r0 = z * W2[t*2 + 0];
    float r1 = z * W2[t*2 + 1];
    #pragma unroll
    for (int o = 1; o < 32; o <<= 1){
        r0 += __shfl_xor(r0, o);
        r1 += __shfl_xor(r1, o);
    }
    if (t == 0 && i < count){
        float z0 = r0 + b2[0], z1 = r1 + b2[1];
        float mm = fmaxf(z0, z1);
        float lse = mm + __logf(__expf(z0 - mm) + __expf(z1 - mm));
        out[(size_t)i*2 + 0] = z0 - lse;
        out[(size_t)i*2 + 1] = z1 - lse;
    }
}

// ---------- per-node P = h @ W1 (no bias) for the edge head ----------
__global__ __launch_bounds__(256) void k_mlp1(
        const float* __restrict__ hf, const float* __restrict__ W1,
        float* __restrict__ P, int count)
{
    __shared__ float sh[8][CH];
    int g = threadIdx.x >> 5;
    int t = threadIdx.x & 31;
    int i = blockIdx.x*8 + g;
    sh[g][t] = (i < count) ? hf[(size_t)i*CH + t] : 0.f;
    __syncthreads();
    float z = 0.f;
    #pragma unroll
    for (int k = 0; k < CH; k++) z += sh[g][k] * W1[k*CH + t];
    if (i < count) P[(size_t)i*CH + t] = z;
}

// ---------- edge head finisher: 8 lanes per edge ----------
__global__ __launch_bounds__(256) void k_edgefin(
        const float* __restrict__ P,
        const int* __restrict__ src, const int* __restrict__ dst,
        const float* __restrict__ b1, const float* __restrict__ W2,
        const float* __restrict__ b2, float* __restrict__ out, int E)
{
    int gt = blockIdx.x*256 + threadIdx.x;
    int e = gt >> 3, sub = gt & 7;
    if (e >= E) return;
    int s = src[e], d = dst[e];
    int c0 = sub*4;
    float4 ps = ld4(P + (size_t)s*CH + c0);
    float4 pd = ld4(P + (size_t)d*CH + c0);
    float4 bb = ld4(b1 + c0);
    float zx = fmaxf(ps.x + pd.x + bb.x, 0.f);
    float zy = fmaxf(ps.y + pd.y + bb.y, 0.f);
    float zz = fmaxf(ps.z + pd.z + bb.z, 0.f);
    float zw = fmaxf(ps.w + pd.w + bb.w, 0.f);
    float r0 = zx*W2[(c0+0)*2] + zy*W2[(c0+1)*2] + zz*W2[(c0+2)*2] + zw*W2[(c0+3)*2];
    float r1 = zx*W2[(c0+0)*2+1] + zy*W2[(c0+1)*2+1] + zz*W2[(c0+2)*2+1] + zw*W2[(c0+3)*2+1];
    #pragma unroll
    for (int o = 1; o < 8; o <<= 1){
        r0 += __shfl_xor(r0, o);
        r1 += __shfl_xor(r1, o);
    }
    if (sub == 0){
        float z0 = r0 + b2[0], z1 = r1 + b2[1];
        float mm = fmaxf(z0, z1);
        float lse = mm + __logf(__expf(z0 - mm) + __expf(z1 - mm));
        float2 o2; o2.x = z0 - lse; o2.y = z1 - lse;
        *reinterpret_cast<float2*>(out + (size_t)e*2) = o2;
    }
}

extern "C" void kernel_launch(void* const* d_in, const int* in_sizes, int n_in,
                              void* d_out, int out_size, void* d_ws, size_t ws_size,
                              hipStream_t stream)
{
    const float* x     = (const float*)d_in[0];
    const int*   ei    = (const int*)d_in[1];
    const float* eattr = (const float*)d_in[2];
    int N = in_sizes[0] / 3;
    int E = in_sizes[2];
    const int* src0 = ei;
    const int* dst0 = ei + E;

    const float *Wl[3], *bl[3], *Wr[3], *br[3], *We[3], *att[3], *bias[3];
    for (int l = 0; l < 3; l++){
        int b = 3 + l*7;
        Wl[l]   = (const float*)d_in[b+0];
        bl[l]   = (const float*)d_in[b+1];
        Wr[l]   = (const float*)d_in[b+2];
        br[l]   = (const float*)d_in[b+3];
        We[l]   = (const float*)d_in[b+4];
        att[l]  = (const float*)d_in[b+5];
        bias[l] = (const float*)d_in[b+6];
    }
    const float* nhW1 = (const float*)d_in[24];
    const float* nhb1 = (const float*)d_in[25];
    const float* nhW2 = (const float*)d_in[26];
    const float* nhb2 = (const float*)d_in[27];
    const float* ehW1 = (const float*)d_in[28];
    const float* ehb1 = (const float*)d_in[29];
    const float* ehW2 = (const float*)d_in[30];
    const float* ehb2 = (const float*)d_in[31];

    char* ws = (char*)d_ws;
    auto alloc = [&](size_t bytes) -> char* {
        char* p = ws;
        ws += (bytes + 255) & ~(size_t)255;
        return p;
    };
    float* H0       = (float*)alloc((size_t)N*HCDIM*4);
    float* XL       = (float*)alloc((size_t)N*HCDIM*4);
    float* XR       = (float*)alloc((size_t)N*HCDIM*4);
    int*   deg      = (int*)alloc((size_t)N*4);
    float* lsum     = (float*)alloc((size_t)N*4);
    float* lattr    = (float*)alloc((size_t)N*4);
    int*   offs     = (int*)alloc((size_t)(N+1)*4);
    int*   cursor   = (int*)alloc((size_t)N*4);
    int*   csr_src  = (int*)alloc((size_t)E*4);
    float* csr_attr = (float*)alloc((size_t)E*4);
    unsigned short* Wt = (unsigned short*)alloc((size_t)512*HCDIM*2);
    float* Pe       = (float*)alloc((size_t)N*CH*4);

    // preprocessing
    k_init<<<(N+255)/256, 256, 0, stream>>>(deg, lsum, cursor, N);
    k_count<<<(E+255)/256, 256, 0, stream>>>(dst0, eattr, deg, lsum, E);
    k_scan<<<1, 1024, 0, stream>>>(deg, offs, N);
    k_loopattr<<<(N+255)/256, 256, 0, stream>>>(deg, lsum, lattr, N);
    k_scatter<<<(E+255)/256, 256, 0, stream>>>(src0, dst0, eattr, offs, cursor,
                                               csr_src, csr_attr, E);

    int gat_grid  = (N + 3) / 4;
    dim3 mfma_grid((N + BM - 1) / BM, 4);

    // layer 0 (din=3, fp32 vector GEMM)
    k_dualgemm<<<(N+15)/16, 256, 0, stream>>>(x, 3, Wl[0], bl[0], Wr[0], br[0], XL, XR, N);
    k_gat<<<gat_grid, 256, 0, stream>>>(XL, XR, csr_src, csr_attr, offs, lattr,
                                        We[0], att[0], bias[0], H0, N, 1);
    // layer 1 (din=256, bf16 MFMA)
    k_cvtw<<<512, 256, 0, stream>>>(Wl[1], Wr[1], Wt);
    k_mfma_gemm<<<mfma_grid, 256, 0, stream>>>(H0, Wt, bl[1], br[1], XL, XR, N);
    k_gat<<<gat_grid, 256, 0, stream>>>(XL, XR, csr_src, csr_attr, offs, lattr,
                                        We[1], att[1], bias[1], H0, N, 1);
    // layer 2 (din=256, bf16 MFMA, concat=false)
    k_cvtw<<<512, 256, 0, stream>>>(Wl[2], Wr[2], Wt);
    k_mfma_gemm<<<mfma_grid, 256, 0, stream>>>(H0, Wt, bl[2], br[2], XL, XR, N);
    k_gat<<<gat_grid, 256, 0, stream>>>(XL, XR, csr_src, csr_attr, offs, lattr,
                                        We[2], att[2], bias[2], H0, N, 0);

    // node head (per-node, cheap)
    float* out_node = (float*)d_out;
    float* out_edge = out_node + (size_t)N*2;
    k_head<<<(N+7)/8, 256, 0, stream>>>(H0, nhW1, nhb1, nhW2, nhb2, out_node, N);

    // edge head: P = H0 @ ehW1 per node, then tiny per-edge finisher
    k_mlp1<<<(N+7)/8, 256, 0, stream>>>(H0, ehW1, Pe, N);
    k_edgefin<<<((size_t)E*8 + 255)/256, 256, 0, stream>>>(Pe, src0, dst0,
                                                           ehb1, ehW2, ehb2, out_edge, E);
}

// Round 4
// 415.036 us; speedup vs baseline: 1.7301x; 1.0514x over previous
//
#include <hip/hip_runtime.h>
#include <math.h>

#define HCDIM 256   // H*C
#define HEADS 8
#define CH 32
#define NEG 0.2f

__device__ __forceinline__ float4 ld4(const float* p){ return *reinterpret_cast<const float4*>(p); }
__device__ __forceinline__ void st4(float* p, float a, float b, float c, float d){
    float4 v; v.x=a; v.y=b; v.z=c; v.w=d; *reinterpret_cast<float4*>(p)=v;
}
__device__ __forceinline__ unsigned short f2bf(float f){
    union { float f; unsigned u; } x; x.f = f;
    unsigned r = x.u + 0x7fff + ((x.u >> 16) & 1);   // RNE
    return (unsigned short)(r >> 16);
}
__device__ __forceinline__ float bf2f(unsigned short u){
    union { unsigned u; float f; } x; x.u = (unsigned)u << 16; return x.f;
}

// ---------- preprocessing ----------
__global__ void k_init(int* deg, float* lsum, int* cursor, int n){
    int i = blockIdx.x*blockDim.x + threadIdx.x;
    if (i < n){ deg[i]=0; lsum[i]=0.f; cursor[i]=0; }
}

__global__ void k_count(const int* __restrict__ dst, const float* __restrict__ eattr,
                        int* deg, float* lsum, int E){
    int e = blockIdx.x*blockDim.x + threadIdx.x;
    if (e < E){
        int d = dst[e];
        atomicAdd(&deg[d], 1);
        atomicAdd(&lsum[d], eattr[e]);
    }
}

// single-block scan: offs[0]=0, offs[i+1]=sum deg[0..i]
__global__ void k_scan(const int* __restrict__ deg, int* __restrict__ offs, int n){
    __shared__ int wsum[16];
    __shared__ int carry;
    int tid = threadIdx.x;            // 1024 threads
    if (tid == 0) carry = 0;
    __syncthreads();
    int lane = tid & 63, wid = tid >> 6;
    for (int base = 0; base < n; base += 1024){
        int i = base + tid;
        int x = (i < n) ? deg[i] : 0;
        #pragma unroll
        for (int o = 1; o < 64; o <<= 1){
            int y = __shfl_up(x, o);
            if (lane >= o) x += y;
        }
        if (lane == 63) wsum[wid] = x;
        __syncthreads();
        if (tid == 0){
            int run = 0;
            for (int w = 0; w < 16; w++){ run += wsum[w]; wsum[w] = run; }
        }
        __syncthreads();
        int pre = (wid > 0 ? wsum[wid-1] : 0) + carry;
        int incl = x + pre;
        if (i < n) offs[i+1] = incl;
        __syncthreads();
        if (tid == 1023) carry = incl;
        __syncthreads();
    }
    if (tid == 0) offs[0] = 0;
}

__global__ void k_loopattr(const int* deg, const float* lsum, float* lattr, int n){
    int i = blockIdx.x*blockDim.x + threadIdx.x;
    if (i < n) lattr[i] = lsum[i] / fmaxf((float)deg[i], 1.0f);
}

__global__ void k_scatter(const int* __restrict__ src, const int* __restrict__ dst,
                          const float* __restrict__ eattr, const int* __restrict__ offs,
                          int* cursor, int* csr_src, float* csr_attr, int E){
    int e = blockIdx.x*blockDim.x + threadIdx.x;
    if (e < E){
        int d = dst[e];
        int pos = offs[d] + atomicAdd(&cursor[d], 1);
        csr_src[pos] = src[e];
        csr_attr[pos] = eattr[e];
    }
}

// ---------- fp32 dual GEMM (layer 0 only, din=3), bf16 outputs ----------
__global__ __launch_bounds__(256) void k_dualgemm(
        const float* __restrict__ h, int din,
        const float* __restrict__ Wl, const float* __restrict__ bl,
        const float* __restrict__ Wr, const float* __restrict__ br,
        unsigned short* __restrict__ xl, unsigned short* __restrict__ xr, int n)
{
    const int ROWS = 16;
    __shared__ float hs[ROWS * HCDIM];
    int row0 = blockIdx.x * ROWS;
    int j = threadIdx.x;

    for (int idx = threadIdx.x; idx < ROWS*din; idx += 256){
        int r = idx / din, k = idx - r*din;
        int row = row0 + r;
        hs[r*din + k] = (row < n) ? h[(size_t)row*din + k] : 0.f;
    }
    __syncthreads();

    float accl[ROWS], accr[ROWS];
    float blj = bl[j], brj = br[j];
    #pragma unroll
    for (int r = 0; r < ROWS; r++){ accl[r] = blj; accr[r] = brj; }

    for (int k = 0; k < din; k++){
        float wl = Wl[k*HCDIM + j], wr = Wr[k*HCDIM + j];
        #pragma unroll
        for (int r = 0; r < ROWS; r++){
            float hv = hs[r*din + k];
            accl[r] += hv*wl;
            accr[r] += hv*wr;
        }
    }
    #pragma unroll
    for (int r = 0; r < ROWS; r++){
        int row = row0 + r;
        if (row < n){
            xl[(size_t)row*HCDIM + j] = f2bf(accl[r]);
            xr[(size_t)row*HCDIM + j] = f2bf(accr[r]);
        }
    }
}

// ---------- weight convert+transpose: Wt[n][k] = bf16(W{l,r}[k][n]) ----------
__global__ __launch_bounds__(256) void k_cvtw(const float* __restrict__ Wl,
                                              const float* __restrict__ Wr,
                                              unsigned short* __restrict__ Wt){
    int idx = blockIdx.x*256 + threadIdx.x;   // idx = nout*256 + k, nout in [0,512)
    int nout = idx >> 8, k = idx & 255;
    float v = (nout < 256) ? Wl[k*HCDIM + nout] : Wr[k*HCDIM + (nout - 256)];
    Wt[idx] = f2bf(v);
}

// ---------- bf16 MFMA GEMM: [xl | xr] = h @ [Wl | Wr] + [bl | br], bf16 out ----------
#define BM 128
#define BN 128
#define BK 32
#define LDK 40   // padded LDS stride (bf16 elems)

typedef __attribute__((ext_vector_type(8))) short bf16x8;
typedef __attribute__((ext_vector_type(4))) float f32x4;

__global__ __launch_bounds__(256) void k_mfma_gemm(
        const float* __restrict__ h,
        const unsigned short* __restrict__ Wt,
        const float* __restrict__ bl, const float* __restrict__ br,
        unsigned short* __restrict__ xl, unsigned short* __restrict__ xr, int n)
{
    __shared__ unsigned short As[BM*LDK];
    __shared__ unsigned short Bs[BN*LDK];
    int tid = threadIdx.x;
    int row0 = blockIdx.x * BM;
    int col0 = blockIdx.y * BN;      // 0,128,256,384 over [Wl|Wr]

    int l = tid & 63, w = tid >> 6;
    int wm = (w >> 1) * 64, wn = (w & 1) * 64;

    f32x4 acc[4][4] = {};

    int srow = tid >> 1;
    int skoff = (tid & 1) * 16;

    for (int kt = 0; kt < 8; ++kt){
        int kb = kt * BK;
        float4 av0, av1, av2, av3;
        int grow = row0 + srow;
        if (grow < n){
            const float* ap = h + (size_t)grow*HCDIM + kb + skoff;
            av0 = ld4(ap); av1 = ld4(ap+4); av2 = ld4(ap+8); av3 = ld4(ap+12);
        } else {
            av0.x=av0.y=av0.z=av0.w=0.f; av1=av0; av2=av0; av3=av0;
        }
        const uint4* bp = reinterpret_cast<const uint4*>(Wt + (size_t)(col0+srow)*HCDIM + kb + skoff);
        uint4 bv0 = bp[0], bv1 = bp[1];

        __syncthreads();

        uint4 apk0, apk1;
        apk0.x = (unsigned)f2bf(av0.x) | ((unsigned)f2bf(av0.y) << 16);
        apk0.y = (unsigned)f2bf(av0.z) | ((unsigned)f2bf(av0.w) << 16);
        apk0.z = (unsigned)f2bf(av1.x) | ((unsigned)f2bf(av1.y) << 16);
        apk0.w = (unsigned)f2bf(av1.z) | ((unsigned)f2bf(av1.w) << 16);
        apk1.x = (unsigned)f2bf(av2.x) | ((unsigned)f2bf(av2.y) << 16);
        apk1.y = (unsigned)f2bf(av2.z) | ((unsigned)f2bf(av2.w) << 16);
        apk1.z = (unsigned)f2bf(av3.x) | ((unsigned)f2bf(av3.y) << 16);
        apk1.w = (unsigned)f2bf(av3.z) | ((unsigned)f2bf(av3.w) << 16);
        *reinterpret_cast<uint4*>(&As[srow*LDK + skoff])     = apk0;
        *reinterpret_cast<uint4*>(&As[srow*LDK + skoff + 8]) = apk1;
        *reinterpret_cast<uint4*>(&Bs[srow*LDK + skoff])     = bv0;
        *reinterpret_cast<uint4*>(&Bs[srow*LDK + skoff + 8]) = bv1;

        __syncthreads();

        bf16x8 af[4], bfr[4];
        #pragma unroll
        for (int m = 0; m < 4; m++)
            af[m] = *reinterpret_cast<const bf16x8*>(&As[(wm + m*16 + (l & 15))*LDK + ((l >> 4)*8)]);
        #pragma unroll
        for (int nn = 0; nn < 4; nn++)
            bfr[nn] = *reinterpret_cast<const bf16x8*>(&Bs[(wn + nn*16 + (l & 15))*LDK + ((l >> 4)*8)]);
        #pragma unroll
        for (int m = 0; m < 4; m++)
            #pragma unroll
            for (int nn = 0; nn < 4; nn++)
                acc[m][nn] = __builtin_amdgcn_mfma_f32_16x16x32_bf16(af[m], bfr[nn], acc[m][nn], 0, 0, 0);
    }

    unsigned short* dstp; const float* biasp; int cbase;
    if (col0 < 256){ dstp = xl; biasp = bl; cbase = col0; }
    else           { dstp = xr; biasp = br; cbase = col0 - 256; }

    #pragma unroll
    for (int nn = 0; nn < 4; nn++){
        int gc = cbase + wn + nn*16 + (l & 15);
        float bb = biasp[gc];
        #pragma unroll
        for (int m = 0; m < 4; m++){
            int r0 = row0 + wm + m*16 + ((l >> 4) * 4);
            #pragma unroll
            for (int v = 0; v < 4; v++){
                int rr = r0 + v;
                if (rr < n) dstp[(size_t)rr*HCDIM + gc] = f2bf(acc[m][nn][v] + bb);
            }
        }
    }
}

// ---------- fused GATv2 edge kernel: one wave per dst node, bf16 gathers ----------
__global__ __launch_bounds__(256) void k_gat(
        const unsigned short* __restrict__ xl, const unsigned short* __restrict__ xr,
        const int* __restrict__ csr_src, const float* __restrict__ csr_attr,
        const int* __restrict__ offs, const float* __restrict__ lattr,
        const float* __restrict__ We, const float* __restrict__ att,
        const float* __restrict__ bias, float* __restrict__ hout,
        int n, int concat)
{
    int wid = threadIdx.x >> 6;
    int lane = threadIdx.x & 63;
    int v = blockIdx.x*4 + wid;
    if (v >= n) return;
    const int cb = lane*4;               // head=lane/8, ch=(lane%8)*4
    float4 We4  = ld4(We + cb);
    float4 att4 = ld4(att + cb);
    ushort4 xr4u = *reinterpret_cast<const ushort4*>(xr + (size_t)v*HCDIM + cb);
    float xrx = bf2f(xr4u.x), xry = bf2f(xr4u.y), xrz = bf2f(xr4u.z), xrw = bf2f(xr4u.w);

    float mh = -INFINITY, s = 0.f;
    float ax = 0.f, ay = 0.f, az = 0.f, aw = 0.f;
    int pbeg = offs[v], pend = offs[v+1];

    for (int p = pbeg - 1; p < pend; ++p){
        int u; float ea;
        if (p < pbeg){ u = v; ea = lattr[v]; }          // self loop
        else         { u = csr_src[p]; ea = csr_attr[p]; }
        ushort4 xu4 = *reinterpret_cast<const ushort4*>(xl + (size_t)u*HCDIM + cb);
        float xux = bf2f(xu4.x), xuy = bf2f(xu4.y), xuz = bf2f(xu4.z), xuw = bf2f(xu4.w);
        float tx = xux + xrx + ea*We4.x;
        float ty = xuy + xry + ea*We4.y;
        float tz = xuz + xrz + ea*We4.z;
        float tw = xuw + xrw + ea*We4.w;
        tx = tx > 0.f ? tx : NEG*tx;
        ty = ty > 0.f ? ty : NEG*ty;
        tz = tz > 0.f ? tz : NEG*tz;
        tw = tw > 0.f ? tw : NEG*tw;
        float part = tx*att4.x + ty*att4.y + tz*att4.z + tw*att4.w;
        part += __shfl_xor(part, 1);
        part += __shfl_xor(part, 2);
        part += __shfl_xor(part, 4);     // logit broadcast within head's 8 lanes
        float nm = fmaxf(mh, part);
        float sc = __expf(mh - nm);
        float w  = __expf(part - nm);
        s  = s*sc + w;
        ax = ax*sc + w*xux;
        ay = ay*sc + w*xuy;
        az = az*sc + w*xuz;
        aw = aw*sc + w*xuw;
        mh = nm;
    }
    float inv = 1.f / s;
    if (concat){
        float4 b4 = ld4(bias + cb);
        st4(hout + (size_t)v*HCDIM + cb,
            fmaxf(ax*inv + b4.x, 0.f), fmaxf(ay*inv + b4.y, 0.f),
            fmaxf(az*inv + b4.z, 0.f), fmaxf(aw*inv + b4.w, 0.f));
    } else {
        float ox = ax*inv, oy = ay*inv, oz = az*inv, ow = aw*inv;
        #pragma unroll
        for (int o = 8; o < 64; o <<= 1){
            ox += __shfl_xor(ox, o); oy += __shfl_xor(oy, o);
            oz += __shfl_xor(oz, o); ow += __shfl_xor(ow, o);
        }
        int c0 = (lane & 7)*4;
        float4 b4 = ld4(bias + c0);
        ox = fmaxf(ox*0.125f + b4.x, 0.f);
        oy = fmaxf(oy*0.125f + b4.y, 0.f);
        oz = fmaxf(oz*0.125f + b4.z, 0.f);
        ow = fmaxf(ow*0.125f + b4.w, 0.f);
        if (lane < 8) st4(hout + (size_t)v*CH + c0, ox, oy, oz, ow);
    }
}

// ---------- node head: 32 threads per node (N only — cheap) ----------
__global__ __launch_bounds__(256) void k_head(
        const float* __restrict__ hf,
        const float* __restrict__ W1, const float* __restrict__ b1,
        const float* __restrict__ W2, const float* __restrict__ b2,
        float* __restrict__ out, int count)
{
    __shared__ float sh[8][CH];
    int g = threadIdx.x >> 5;
    int t = threadIdx.x & 31;
    int i = blockIdx.x*8 + g;
    float hv = (i < count) ? hf[(size_t)i*CH + t] : 0.f;
    sh[g][t] = hv;
    __syncthreads();
    float z = b1[t];
    #pragma unroll
    for (int k = 0; k < CH; k++) z += sh[g][k] * W1[k*CH + t];
    z = fmaxf(z, 0.f);
    float r0 = z * W2[t*2 + 0];
    float r1 = z * W2[t*2 + 1];
    #pragma unroll
    for (int o = 1; o < 32; o <<= 1){
        r0 += __shfl_xor(r0, o);
        r1 += __shfl_xor(r1, o);
    }
    if (t == 0 && i < count){
        float z0 = r0 + b2[0], z1 = r1 + b2[1];
        float mm = fmaxf(z0, z1);
        float lse = mm + __logf(__expf(z0 - mm) + __expf(z1 - mm));
        out[(size_t)i*2 + 0] = z0 - lse;
        out[(size_t)i*2 + 1] = z1 - lse;
    }
}

// ---------- per-node P = h @ W1 (no bias) for the edge head ----------
__global__ __launch_bounds__(256) void k_mlp1(
        const float* __restrict__ hf, const float* __restrict__ W1,
        float* __restrict__ P, int count)
{
    __shared__ float sh[8][CH];
    int g = threadIdx.x >> 5;
    int t = threadIdx.x & 31;
    int i = blockIdx.x*8 + g;
    sh[g][t] = (i < count) ? hf[(size_t)i*CH + t] : 0.f;
    __syncthreads();
    float z = 0.f;
    #pragma unroll
    for (int k = 0; k < CH; k++) z += sh[g][k] * W1[k*CH + t];
    if (i < count) P[(size_t)i*CH + t] = z;
}

// ---------- edge head finisher: 8 lanes per edge ----------
__global__ __launch_bounds__(256) void k_edgefin(
        const float* __restrict__ P,
        const int* __restrict__ src, const int* __restrict__ dst,
        const float* __restrict__ b1, const float* __restrict__ W2,
        const float* __restrict__ b2, float* __restrict__ out, int E)
{
    int gt = blockIdx.x*256 + threadIdx.x;
    int e = gt >> 3, sub = gt & 7;
    if (e >= E) return;
    int s = src[e], d = dst[e];
    int c0 = sub*4;
    float4 ps = ld4(P + (size_t)s*CH + c0);
    float4 pd = ld4(P + (size_t)d*CH + c0);
    float4 bb = ld4(b1 + c0);
    float zx = fmaxf(ps.x + pd.x + bb.x, 0.f);
    float zy = fmaxf(ps.y + pd.y + bb.y, 0.f);
    float zz = fmaxf(ps.z + pd.z + bb.z, 0.f);
    float zw = fmaxf(ps.w + pd.w + bb.w, 0.f);
    float r0 = zx*W2[(c0+0)*2] + zy*W2[(c0+1)*2] + zz*W2[(c0+2)*2] + zw*W2[(c0+3)*2];
    float r1 = zx*W2[(c0+0)*2+1] + zy*W2[(c0+1)*2+1] + zz*W2[(c0+2)*2+1] + zw*W2[(c0+3)*2+1];
    #pragma unroll
    for (int o = 1; o < 8; o <<= 1){
        r0 += __shfl_xor(r0, o);
        r1 += __shfl_xor(r1, o);
    }
    if (sub == 0){
        float z0 = r0 + b2[0], z1 = r1 + b2[1];
        float mm = fmaxf(z0, z1);
        float lse = mm + __logf(__expf(z0 - mm) + __expf(z1 - mm));
        float2 o2; o2.x = z0 - lse; o2.y = z1 - lse;
        *reinterpret_cast<float2*>(out + (size_t)e*2) = o2;
    }
}

extern "C" void kernel_launch(void* const* d_in, const int* in_sizes, int n_in,
                              void* d_out, int out_size, void* d_ws, size_t ws_size,
                              hipStream_t stream)
{
    const float* x     = (const float*)d_in[0];
    const int*   ei    = (const int*)d_in[1];
    const float* eattr = (const float*)d_in[2];
    int N = in_sizes[0] / 3;
    int E = in_sizes[2];
    const int* src0 = ei;
    const int* dst0 = ei + E;

    const float *Wl[3], *bl[3], *Wr[3], *br[3], *We[3], *att[3], *bias[3];
    for (int l = 0; l < 3; l++){
        int b = 3 + l*7;
        Wl[l]   = (const float*)d_in[b+0];
        bl[l]   = (const float*)d_in[b+1];
        Wr[l]   = (const float*)d_in[b+2];
        br[l]   = (const float*)d_in[b+3];
        We[l]   = (const float*)d_in[b+4];
        att[l]  = (const float*)d_in[b+5];
        bias[l] = (const float*)d_in[b+6];
    }
    const float* nhW1 = (const float*)d_in[24];
    const float* nhb1 = (const float*)d_in[25];
    const float* nhW2 = (const float*)d_in[26];
    const float* nhb2 = (const float*)d_in[27];
    const float* ehW1 = (const float*)d_in[28];
    const float* ehb1 = (const float*)d_in[29];
    const float* ehW2 = (const float*)d_in[30];
    const float* ehb2 = (const float*)d_in[31];

    char* ws = (char*)d_ws;
    auto alloc = [&](size_t bytes) -> char* {
        char* p = ws;
        ws += (bytes + 255) & ~(size_t)255;
        return p;
    };
    float* H0                = (float*)alloc((size_t)N*HCDIM*4);
    unsigned short* XL       = (unsigned short*)alloc((size_t)N*HCDIM*2);
    unsigned short* XR       = (unsigned short*)alloc((size_t)N*HCDIM*2);
    int*   deg      = (int*)alloc((size_t)N*4);
    float* lsum     = (float*)alloc((size_t)N*4);
    float* lattr    = (float*)alloc((size_t)N*4);
    int*   offs     = (int*)alloc((size_t)(N+1)*4);
    int*   cursor   = (int*)alloc((size_t)N*4);
    int*   csr_src  = (int*)alloc((size_t)E*4);
    float* csr_attr = (float*)alloc((size_t)E*4);
    unsigned short* Wt = (unsigned short*)alloc((size_t)512*HCDIM*2);
    float* Pe       = (float*)alloc((size_t)N*CH*4);

    // preprocessing
    k_init<<<(N+255)/256, 256, 0, stream>>>(deg, lsum, cursor, N);
    k_count<<<(E+255)/256, 256, 0, stream>>>(dst0, eattr, deg, lsum, E);
    k_scan<<<1, 1024, 0, stream>>>(deg, offs, N);
    k_loopattr<<<(N+255)/256, 256, 0, stream>>>(deg, lsum, lattr, N);
    k_scatter<<<(E+255)/256, 256, 0, stream>>>(src0, dst0, eattr, offs, cursor,
                                               csr_src, csr_attr, E);

    int gat_grid  = (N + 3) / 4;
    dim3 mfma_grid((N + BM - 1) / BM, 4);

    // layer 0 (din=3, fp32 vector GEMM -> bf16 xl/xr)
    k_dualgemm<<<(N+15)/16, 256, 0, stream>>>(x, 3, Wl[0], bl[0], Wr[0], br[0], XL, XR, N);
    k_gat<<<gat_grid, 256, 0, stream>>>(XL, XR, csr_src, csr_attr, offs, lattr,
                                        We[0], att[0], bias[0], H0, N, 1);
    // layer 1 (din=256, bf16 MFMA)
    k_cvtw<<<512, 256, 0, stream>>>(Wl[1], Wr[1], Wt);
    k_mfma_gemm<<<mfma_grid, 256, 0, stream>>>(H0, Wt, bl[1], br[1], XL, XR, N);
    k_gat<<<gat_grid, 256, 0, stream>>>(XL, XR, csr_src, csr_attr, offs, lattr,
                                        We[1], att[1], bias[1], H0, N, 1);
    // layer 2 (din=256, bf16 MFMA, concat=false)
    k_cvtw<<<512, 256, 0, stream>>>(Wl[2], Wr[2], Wt);
    k_mfma_gemm<<<mfma_grid, 256, 0, stream>>>(H0, Wt, bl[2], br[2], XL, XR, N);
    k_gat<<<gat_grid, 256, 0, stream>>>(XL, XR, csr_src, csr_attr, offs, lattr,
                                        We[2], att[2], bias[2], H0, N, 0);

    // node head (per-node, cheap)
    float* out_node = (float*)d_out;
    float* out_edge = out_node + (size_t)N*2;
    k_head<<<(N+7)/8, 256, 0, stream>>>(H0, nhW1, nhb1, nhW2, nhb2, out_node, N);

    // edge head: P = H0 @ ehW1 per node, then tiny per-edge finisher
    k_mlp1<<<(N+7)/8, 256, 0, stream>>>(H0, ehW1, Pe, N);
    k_edgefin<<<((size_t)E*8 + 255)/256, 256, 0, stream>>>(Pe, src0, dst0,
                                                           ehb1, ehW2, ehb2, out_edge, E);
}

// Round 5
// 384.793 us; speedup vs baseline: 1.8661x; 1.0786x over previous
//
#include <hip/hip_runtime.h>
#include <math.h>

#define HCDIM 256   // H*C
#define HEADS 8
#define CH 32
#define NEG 0.2f

__device__ __forceinline__ float4 ld4(const float* p){ return *reinterpret_cast<const float4*>(p); }
__device__ __forceinline__ void st4(float* p, float a, float b, float c, float d){
    float4 v; v.x=a; v.y=b; v.z=c; v.w=d; *reinterpret_cast<float4*>(p)=v;
}
__device__ __forceinline__ unsigned short f2bf(float f){
    union { float f; unsigned u; } x; x.f = f;
    unsigned r = x.u + 0x7fff + ((x.u >> 16) & 1);   // RNE
    return (unsigned short)(r >> 16);
}
__device__ __forceinline__ float bf2f(unsigned short u){
    union { unsigned u; float f; } x; x.u = (unsigned)u << 16; return x.f;
}

// ---------- preprocessing ----------
__global__ void k_init(int* deg, float* lsum, int* cursor, int n){
    int i = blockIdx.x*blockDim.x + threadIdx.x;
    if (i < n){ deg[i]=0; lsum[i]=0.f; cursor[i]=0; }
}

__global__ void k_count(const int* __restrict__ dst, const float* __restrict__ eattr,
                        int* deg, float* lsum, int E){
    int e = blockIdx.x*blockDim.x + threadIdx.x;
    if (e < E){
        int d = dst[e];
        atomicAdd(&deg[d], 1);
        atomicAdd(&lsum[d], eattr[e]);
    }
}

// single-block scan: offs[0]=0, offs[i+1]=sum deg[0..i]
__global__ void k_scan(const int* __restrict__ deg, int* __restrict__ offs, int n){
    __shared__ int wsum[16];
    __shared__ int carry;
    int tid = threadIdx.x;            // 1024 threads
    if (tid == 0) carry = 0;
    __syncthreads();
    int lane = tid & 63, wid = tid >> 6;
    for (int base = 0; base < n; base += 1024){
        int i = base + tid;
        int x = (i < n) ? deg[i] : 0;
        #pragma unroll
        for (int o = 1; o < 64; o <<= 1){
            int y = __shfl_up(x, o);
            if (lane >= o) x += y;
        }
        if (lane == 63) wsum[wid] = x;
        __syncthreads();
        if (tid == 0){
            int run = 0;
            for (int w = 0; w < 16; w++){ run += wsum[w]; wsum[w] = run; }
        }
        __syncthreads();
        int pre = (wid > 0 ? wsum[wid-1] : 0) + carry;
        int incl = x + pre;
        if (i < n) offs[i+1] = incl;
        __syncthreads();
        if (tid == 1023) carry = incl;
        __syncthreads();
    }
    if (tid == 0) offs[0] = 0;
}

__global__ void k_loopattr(const int* deg, const float* lsum, float* lattr, int n){
    int i = blockIdx.x*blockDim.x + threadIdx.x;
    if (i < n) lattr[i] = lsum[i] / fmaxf((float)deg[i], 1.0f);
}

__global__ void k_scatter(const int* __restrict__ src, const int* __restrict__ dst,
                          const float* __restrict__ eattr, const int* __restrict__ offs,
                          int* cursor, int2* csr, int E){
    int e = blockIdx.x*blockDim.x + threadIdx.x;
    if (e < E){
        int d = dst[e];
        int pos = offs[d] + atomicAdd(&cursor[d], 1);
        int2 pk; pk.x = src[e]; pk.y = __float_as_int(eattr[e]);
        csr[pos] = pk;
    }
}

// ---------- fp32 dual GEMM (layer 0 only, din=3), bf16 outputs ----------
__global__ __launch_bounds__(256) void k_dualgemm(
        const float* __restrict__ h, int din,
        const float* __restrict__ Wl, const float* __restrict__ bl,
        const float* __restrict__ Wr, const float* __restrict__ br,
        unsigned short* __restrict__ xl, unsigned short* __restrict__ xr, int n)
{
    const int ROWS = 16;
    __shared__ float hs[ROWS * HCDIM];
    int row0 = blockIdx.x * ROWS;
    int j = threadIdx.x;

    for (int idx = threadIdx.x; idx < ROWS*din; idx += 256){
        int r = idx / din, k = idx - r*din;
        int row = row0 + r;
        hs[r*din + k] = (row < n) ? h[(size_t)row*din + k] : 0.f;
    }
    __syncthreads();

    float accl[ROWS], accr[ROWS];
    float blj = bl[j], brj = br[j];
    #pragma unroll
    for (int r = 0; r < ROWS; r++){ accl[r] = blj; accr[r] = brj; }

    for (int k = 0; k < din; k++){
        float wl = Wl[k*HCDIM + j], wr = Wr[k*HCDIM + j];
        #pragma unroll
        for (int r = 0; r < ROWS; r++){
            float hv = hs[r*din + k];
            accl[r] += hv*wl;
            accr[r] += hv*wr;
        }
    }
    #pragma unroll
    for (int r = 0; r < ROWS; r++){
        int row = row0 + r;
        if (row < n){
            xl[(size_t)row*HCDIM + j] = f2bf(accl[r]);
            xr[(size_t)row*HCDIM + j] = f2bf(accr[r]);
        }
    }
}

// ---------- weight convert+transpose: Wt[n][k] = bf16(W{l,r}[k][n]) ----------
__global__ __launch_bounds__(256) void k_cvtw(const float* __restrict__ Wl,
                                              const float* __restrict__ Wr,
                                              unsigned short* __restrict__ Wt){
    int idx = blockIdx.x*256 + threadIdx.x;   // idx = nout*256 + k, nout in [0,512)
    int nout = idx >> 8, k = idx & 255;
    float v = (nout < 256) ? Wl[k*HCDIM + nout] : Wr[k*HCDIM + (nout - 256)];
    Wt[idx] = f2bf(v);
}

// ---------- bf16 MFMA GEMM: [xl | xr] = h @ [Wl | Wr] + [bl | br], bf16 out ----------
#define BM 128
#define BN 128
#define BK 32
#define LDK 40   // padded LDS stride (bf16 elems)

typedef __attribute__((ext_vector_type(8))) short bf16x8;
typedef __attribute__((ext_vector_type(4))) float f32x4;

__global__ __launch_bounds__(256) void k_mfma_gemm(
        const float* __restrict__ h,
        const unsigned short* __restrict__ Wt,
        const float* __restrict__ bl, const float* __restrict__ br,
        unsigned short* __restrict__ xl, unsigned short* __restrict__ xr, int n)
{
    __shared__ unsigned short As[BM*LDK];
    __shared__ unsigned short Bs[BN*LDK];
    int tid = threadIdx.x;
    int row0 = blockIdx.x * BM;
    int col0 = blockIdx.y * BN;      // 0,128,256,384 over [Wl|Wr]

    int l = tid & 63, w = tid >> 6;
    int wm = (w >> 1) * 64, wn = (w & 1) * 64;

    f32x4 acc[4][4] = {};

    int srow = tid >> 1;
    int skoff = (tid & 1) * 16;

    for (int kt = 0; kt < 8; ++kt){
        int kb = kt * BK;
        float4 av0, av1, av2, av3;
        int grow = row0 + srow;
        if (grow < n){
            const float* ap = h + (size_t)grow*HCDIM + kb + skoff;
            av0 = ld4(ap); av1 = ld4(ap+4); av2 = ld4(ap+8); av3 = ld4(ap+12);
        } else {
            av0.x=av0.y=av0.z=av0.w=0.f; av1=av0; av2=av0; av3=av0;
        }
        const uint4* bp = reinterpret_cast<const uint4*>(Wt + (size_t)(col0+srow)*HCDIM + kb + skoff);
        uint4 bv0 = bp[0], bv1 = bp[1];

        __syncthreads();

        uint4 apk0, apk1;
        apk0.x = (unsigned)f2bf(av0.x) | ((unsigned)f2bf(av0.y) << 16);
        apk0.y = (unsigned)f2bf(av0.z) | ((unsigned)f2bf(av0.w) << 16);
        apk0.z = (unsigned)f2bf(av1.x) | ((unsigned)f2bf(av1.y) << 16);
        apk0.w = (unsigned)f2bf(av1.z) | ((unsigned)f2bf(av1.w) << 16);
        apk1.x = (unsigned)f2bf(av2.x) | ((unsigned)f2bf(av2.y) << 16);
        apk1.y = (unsigned)f2bf(av2.z) | ((unsigned)f2bf(av2.w) << 16);
        apk1.z = (unsigned)f2bf(av3.x) | ((unsigned)f2bf(av3.y) << 16);
        apk1.w = (unsigned)f2bf(av3.z) | ((unsigned)f2bf(av3.w) << 16);
        *reinterpret_cast<uint4*>(&As[srow*LDK + skoff])     = apk0;
        *reinterpret_cast<uint4*>(&As[srow*LDK + skoff + 8]) = apk1;
        *reinterpret_cast<uint4*>(&Bs[srow*LDK + skoff])     = bv0;
        *reinterpret_cast<uint4*>(&Bs[srow*LDK + skoff + 8]) = bv1;

        __syncthreads();

        bf16x8 af[4], bfr[4];
        #pragma unroll
        for (int m = 0; m < 4; m++)
            af[m] = *reinterpret_cast<const bf16x8*>(&As[(wm + m*16 + (l & 15))*LDK + ((l >> 4)*8)]);
        #pragma unroll
        for (int nn = 0; nn < 4; nn++)
            bfr[nn] = *reinterpret_cast<const bf16x8*>(&Bs[(wn + nn*16 + (l & 15))*LDK + ((l >> 4)*8)]);
        #pragma unroll
        for (int m = 0; m < 4; m++)
            #pragma unroll
            for (int nn = 0; nn < 4; nn++)
                acc[m][nn] = __builtin_amdgcn_mfma_f32_16x16x32_bf16(af[m], bfr[nn], acc[m][nn], 0, 0, 0);
    }

    unsigned short* dstp; const float* biasp; int cbase;
    if (col0 < 256){ dstp = xl; biasp = bl; cbase = col0; }
    else           { dstp = xr; biasp = br; cbase = col0 - 256; }

    #pragma unroll
    for (int nn = 0; nn < 4; nn++){
        int gc = cbase + wn + nn*16 + (l & 15);
        float bb = biasp[gc];
        #pragma unroll
        for (int m = 0; m < 4; m++){
            int r0 = row0 + wm + m*16 + ((l >> 4) * 4);
            #pragma unroll
            for (int v = 0; v < 4; v++){
                int rr = r0 + v;
                if (rr < n) dstp[(size_t)rr*HCDIM + gc] = f2bf(acc[m][nn][v] + bb);
            }
        }
    }
}

// ---------- fused GATv2 edge kernel: TWO waves per dst node (even/odd edges) ----------
// wave pair merges online-softmax states via LDS; distance-2 csr prefetch +
// distance-1 gather prefetch hides L2-miss latency.
__global__ __launch_bounds__(256) void k_gat(
        const unsigned short* __restrict__ xl, const unsigned short* __restrict__ xr,
        const int2* __restrict__ csr,
        const int* __restrict__ offs, const float* __restrict__ lattr,
        const float* __restrict__ We, const float* __restrict__ att,
        const float* __restrict__ bias, float* __restrict__ hout,
        int n, int concat)
{
    __shared__ float smg[4][64][6];
    int wid  = threadIdx.x >> 6;     // 0..3
    int lane = threadIdx.x & 63;
    int pair = wid >> 1;             // node slot in block
    int half = wid & 1;              // 0: even csr positions + self loop; 1: odd
    int v = blockIdx.x*2 + pair;
    bool valid = (v < n);

    const int cb = lane*4;           // head=lane/8, ch=(lane%8)*4
    float4 We4  = ld4(We + cb);
    float4 att4 = ld4(att + cb);
    float xrx=0,xry=0,xrz=0,xrw=0;
    int pbeg=0, pend=0;
    float la = 0.f;
    if (valid){
        ushort4 xr4u = *reinterpret_cast<const ushort4*>(xr + (size_t)v*HCDIM + cb);
        xrx = bf2f(xr4u.x); xry = bf2f(xr4u.y); xrz = bf2f(xr4u.z); xrw = bf2f(xr4u.w);
        pbeg = offs[v]; pend = offs[v+1];
        la = lattr[v];
    }

    float mh = -INFINITY, s = 0.f;
    float ax = 0.f, ay = 0.f, az = 0.f, aw = 0.f;

    auto edge_step = [&](ushort4 xu4, float ea){
        float xux = bf2f(xu4.x), xuy = bf2f(xu4.y), xuz = bf2f(xu4.z), xuw = bf2f(xu4.w);
        float tx = xux + xrx + ea*We4.x;
        float ty = xuy + xry + ea*We4.y;
        float tz = xuz + xrz + ea*We4.z;
        float tw = xuw + xrw + ea*We4.w;
        tx = tx > 0.f ? tx : NEG*tx;
        ty = ty > 0.f ? ty : NEG*ty;
        tz = tz > 0.f ? tz : NEG*tz;
        tw = tw > 0.f ? tw : NEG*tw;
        float part = tx*att4.x + ty*att4.y + tz*att4.z + tw*att4.w;
        part += __shfl_xor(part, 1);
        part += __shfl_xor(part, 2);
        part += __shfl_xor(part, 4);   // logit uniform within head's 8 lanes
        float nm = fmaxf(mh, part);
        float sc = __expf(mh - nm);    // exp(-inf)=0 on first edge
        float w  = __expf(part - nm);
        s  = s*sc + w;
        ax = ax*sc + w*xux;
        ay = ay*sc + w*xuy;
        az = az*sc + w*xuz;
        aw = aw*sc + w*xuw;
        mh = nm;
    };

    if (half == 0 && valid){
        ushort4 xv4 = *reinterpret_cast<const ushort4*>(xl + (size_t)v*HCDIM + cb);
        edge_step(xv4, la);            // self loop
    }

    // pipelined stride-2 edge loop: eA = current entry, eB = next entry (dist 2),
    // xuA = current gather (dist 1)
    int p = pbeg + half;
    int2 eA, eB; ushort4 xuA;
    if (p < pend){
        eA = csr[p];
        xuA = *reinterpret_cast<const ushort4*>(xl + ((size_t)eA.x << 8) + cb);
        if (p + 2 < pend) eB = csr[p + 2];
    }
    for (; p < pend; p += 2){
        ushort4 cur = xuA;
        float ea = __int_as_float(eA.y);
        if (p + 2 < pend){
            xuA = *reinterpret_cast<const ushort4*>(xl + ((size_t)eB.x << 8) + cb);
            eA = eB;
            if (p + 4 < pend) eB = csr[p + 4];
        }
        edge_step(cur, ea);
    }

    // merge the two halves' online-softmax states
    smg[wid][lane][0] = mh; smg[wid][lane][1] = s;
    smg[wid][lane][2] = ax; smg[wid][lane][3] = ay;
    smg[wid][lane][4] = az; smg[wid][lane][5] = aw;
    __syncthreads();
    if (half != 0 || !valid) return;

    float m2  = smg[wid+1][lane][0];
    float s2  = smg[wid+1][lane][1];
    float a2x = smg[wid+1][lane][2];
    float a2y = smg[wid+1][lane][3];
    float a2z = smg[wid+1][lane][4];
    float a2w = smg[wid+1][lane][5];
    float M  = fmaxf(mh, m2);          // mh finite (self loop) => M finite
    float c1 = __expf(mh - M);
    float c2 = __expf(m2 - M);         // exp(-inf)=0 when half1 empty
    s  = s*c1 + s2*c2;
    ax = ax*c1 + a2x*c2;
    ay = ay*c1 + a2y*c2;
    az = az*c1 + a2z*c2;
    aw = aw*c1 + a2w*c2;

    float inv = 1.f / s;
    if (concat){
        float4 b4 = ld4(bias + cb);
        st4(hout + (size_t)v*HCDIM + cb,
            fmaxf(ax*inv + b4.x, 0.f), fmaxf(ay*inv + b4.y, 0.f),
            fmaxf(az*inv + b4.z, 0.f), fmaxf(aw*inv + b4.w, 0.f));
    } else {
        float ox = ax*inv, oy = ay*inv, oz = az*inv, ow = aw*inv;
        #pragma unroll
        for (int o = 8; o < 64; o <<= 1){
            ox += __shfl_xor(ox, o); oy += __shfl_xor(oy, o);
            oz += __shfl_xor(oz, o); ow += __shfl_xor(ow, o);
        }
        int c0 = (lane & 7)*4;
        float4 b4 = ld4(bias + c0);
        ox = fmaxf(ox*0.125f + b4.x, 0.f);
        oy = fmaxf(oy*0.125f + b4.y, 0.f);
        oz = fmaxf(oz*0.125f + b4.z, 0.f);
        ow = fmaxf(ow*0.125f + b4.w, 0.f);
        if (lane < 8) st4(hout + (size_t)v*CH + c0, ox, oy, oz, ow);
    }
}

// ---------- node head: 32 threads per node (N only — cheap) ----------
__global__ __launch_bounds__(256) void k_head(
        const float* __restrict__ hf,
        const float* __restrict__ W1, const float* __restrict__ b1,
        const float* __restrict__ W2, const float* __restrict__ b2,
        float* __restrict__ out, int count)
{
    __shared__ float sh[8][CH];
    int g = threadIdx.x >> 5;
    int t = threadIdx.x & 31;
    int i = blockIdx.x*8 + g;
    float hv = (i < count) ? hf[(size_t)i*CH + t] : 0.f;
    sh[g][t] = hv;
    __syncthreads();
    float z = b1[t];
    #pragma unroll
    for (int k = 0; k < CH; k++) z += sh[g][k] * W1[k*CH + t];
    z = fmaxf(z, 0.f);
    float r0 = z * W2[t*2 + 0];
    float r1 = z * W2[t*2 + 1];
    #pragma unroll
    for (int o = 1; o < 32; o <<= 1){
        r0 += __shfl_xor(r0, o);
        r1 += __shfl_xor(r1, o);
    }
    if (t == 0 && i < count){
        float z0 = r0 + b2[0], z1 = r1 + b2[1];
        float mm = fmaxf(z0, z1);
        float lse = mm + __logf(__expf(z0 - mm) + __expf(z1 - mm));
        out[(size_t)i*2 + 0] = z0 - lse;
        out[(size_t)i*2 + 1] = z1 - lse;
    }
}

// ---------- per-node P = h @ W1 (no bias) for the edge head ----------
__global__ __launch_bounds__(256) void k_mlp1(
        const float* __restrict__ hf, const float* __restrict__ W1,
        float* __restrict__ P, int count)
{
    __shared__ float sh[8][CH];
    int g = threadIdx.x >> 5;
    int t = threadIdx.x & 31;
    int i = blockIdx.x*8 + g;
    sh[g][t] = (i < count) ? hf[(size_t)i*CH + t] : 0.f;
    __syncthreads();
    float z = 0.f;
    #pragma unroll
    for (int k = 0; k < CH; k++) z += sh[g][k] * W1[k*CH + t];
    if (i < count) P[(size_t)i*CH + t] = z;
}

// ---------- edge head finisher: 8 lanes per edge ----------
__global__ __launch_bounds__(256) void k_edgefin(
        const float* __restrict__ P,
        const int* __restrict__ src, const int* __restrict__ dst,
        const float* __restrict__ b1, const float* __restrict__ W2,
        const float* __restrict__ b2, float* __restrict__ out, int E)
{
    int gt = blockIdx.x*256 + threadIdx.x;
    int e = gt >> 3, sub = gt & 7;
    if (e >= E) return;
    int s = src[e], d = dst[e];
    int c0 = sub*4;
    float4 ps = ld4(P + (size_t)s*CH + c0);
    float4 pd = ld4(P + (size_t)d*CH + c0);
    float4 bb = ld4(b1 + c0);
    float zx = fmaxf(ps.x + pd.x + bb.x, 0.f);
    float zy = fmaxf(ps.y + pd.y + bb.y, 0.f);
    float zz = fmaxf(ps.z + pd.z + bb.z, 0.f);
    float zw = fmaxf(ps.w + pd.w + bb.w, 0.f);
    float r0 = zx*W2[(c0+0)*2] + zy*W2[(c0+1)*2] + zz*W2[(c0+2)*2] + zw*W2[(c0+3)*2];
    float r1 = zx*W2[(c0+0)*2+1] + zy*W2[(c0+1)*2+1] + zz*W2[(c0+2)*2+1] + zw*W2[(c0+3)*2+1];
    #pragma unroll
    for (int o = 1; o < 8; o <<= 1){
        r0 += __shfl_xor(r0, o);
        r1 += __shfl_xor(r1, o);
    }
    if (sub == 0){
        float z0 = r0 + b2[0], z1 = r1 + b2[1];
        float mm = fmaxf(z0, z1);
        float lse = mm + __logf(__expf(z0 - mm) + __expf(z1 - mm));
        float2 o2; o2.x = z0 - lse; o2.y = z1 - lse;
        *reinterpret_cast<float2*>(out + (size_t)e*2) = o2;
    }
}

extern "C" void kernel_launch(void* const* d_in, const int* in_sizes, int n_in,
                              void* d_out, int out_size, void* d_ws, size_t ws_size,
                              hipStream_t stream)
{
    const float* x     = (const float*)d_in[0];
    const int*   ei    = (const int*)d_in[1];
    const float* eattr = (const float*)d_in[2];
    int N = in_sizes[0] / 3;
    int E = in_sizes[2];
    const int* src0 = ei;
    const int* dst0 = ei + E;

    const float *Wl[3], *bl[3], *Wr[3], *br[3], *We[3], *att[3], *bias[3];
    for (int l = 0; l < 3; l++){
        int b = 3 + l*7;
        Wl[l]   = (const float*)d_in[b+0];
        bl[l]   = (const float*)d_in[b+1];
        Wr[l]   = (const float*)d_in[b+2];
        br[l]   = (const float*)d_in[b+3];
        We[l]   = (const float*)d_in[b+4];
        att[l]  = (const float*)d_in[b+5];
        bias[l] = (const float*)d_in[b+6];
    }
    const float* nhW1 = (const float*)d_in[24];
    const float* nhb1 = (const float*)d_in[25];
    const float* nhW2 = (const float*)d_in[26];
    const float* nhb2 = (const float*)d_in[27];
    const float* ehW1 = (const float*)d_in[28];
    const float* ehb1 = (const float*)d_in[29];
    const float* ehW2 = (const float*)d_in[30];
    const float* ehb2 = (const float*)d_in[31];

    char* ws = (char*)d_ws;
    auto alloc = [&](size_t bytes) -> char* {
        char* p = ws;
        ws += (bytes + 255) & ~(size_t)255;
        return p;
    };
    float* H0                = (float*)alloc((size_t)N*HCDIM*4);
    unsigned short* XL       = (unsigned short*)alloc((size_t)N*HCDIM*2);
    unsigned short* XR       = (unsigned short*)alloc((size_t)N*HCDIM*2);
    int*   deg      = (int*)alloc((size_t)N*4);
    float* lsum     = (float*)alloc((size_t)N*4);
    float* lattr    = (float*)alloc((size_t)N*4);
    int*   offs     = (int*)alloc((size_t)(N+1)*4);
    int*   cursor   = (int*)alloc((size_t)N*4);
    int2*  csr      = (int2*)alloc((size_t)E*8);
    unsigned short* Wt = (unsigned short*)alloc((size_t)512*HCDIM*2);
    float* Pe       = (float*)alloc((size_t)N*CH*4);

    // preprocessing
    k_init<<<(N+255)/256, 256, 0, stream>>>(deg, lsum, cursor, N);
    k_count<<<(E+255)/256, 256, 0, stream>>>(dst0, eattr, deg, lsum, E);
    k_scan<<<1, 1024, 0, stream>>>(deg, offs, N);
    k_loopattr<<<(N+255)/256, 256, 0, stream>>>(deg, lsum, lattr, N);
    k_scatter<<<(E+255)/256, 256, 0, stream>>>(src0, dst0, eattr, offs, cursor, csr, E);

    int gat_grid  = (N + 1) / 2;     // 2 nodes per block, 2 waves per node
    dim3 mfma_grid((N + BM - 1) / BM, 4);

    // layer 0 (din=3, fp32 vector GEMM -> bf16 xl/xr)
    k_dualgemm<<<(N+15)/16, 256, 0, stream>>>(x, 3, Wl[0], bl[0], Wr[0], br[0], XL, XR, N);
    k_gat<<<gat_grid, 256, 0, stream>>>(XL, XR, csr, offs, lattr,
                                        We[0], att[0], bias[0], H0, N, 1);
    // layer 1 (din=256, bf16 MFMA)
    k_cvtw<<<512, 256, 0, stream>>>(Wl[1], Wr[1], Wt);
    k_mfma_gemm<<<mfma_grid, 256, 0, stream>>>(H0, Wt, bl[1], br[1], XL, XR, N);
    k_gat<<<gat_grid, 256, 0, stream>>>(XL, XR, csr, offs, lattr,
                                        We[1], att[1], bias[1], H0, N, 1);
    // layer 2 (din=256, bf16 MFMA, concat=false)
    k_cvtw<<<512, 256, 0, stream>>>(Wl[2], Wr[2], Wt);
    k_mfma_gemm<<<mfma_grid, 256, 0, stream>>>(H0, Wt, bl[2], br[2], XL, XR, N);
    k_gat<<<gat_grid, 256, 0, stream>>>(XL, XR, csr, offs, lattr,
                                        We[2], att[2], bias[2], H0, N, 0);

    // node head (per-node, cheap)
    float* out_node = (float*)d_out;
    float* out_edge = out_node + (size_t)N*2;
    k_head<<<(N+7)/8, 256, 0, stream>>>(H0, nhW1, nhb1, nhW2, nhb2, out_node, N);

    // edge head: P = H0 @ ehW1 per node, then tiny per-edge finisher
    k_mlp1<<<(N+7)/8, 256, 0, stream>>>(H0, ehW1, Pe, N);
    k_edgefin<<<((size_t)E*8 + 255)/256, 256, 0, stream>>>(Pe, src0, dst0,
                                                           ehb1, ehW2, ehb2, out_edge, E);
}

// Round 6
// 344.657 us; speedup vs baseline: 2.0834x; 1.1165x over previous
//
#include <hip/hip_runtime.h>
#include <math.h>

#define HCDIM 256   // H*C
#define HEADS 8
#define CH 32
#define NEG 0.2f

__device__ __forceinline__ float4 ld4(const float* p){ return *reinterpret_cast<const float4*>(p); }
__device__ __forceinline__ void st4(float* p, float a, float b, float c, float d){
    float4 v; v.x=a; v.y=b; v.z=c; v.w=d; *reinterpret_cast<float4*>(p)=v;
}
__device__ __forceinline__ unsigned short f2bf(float f){
    union { float f; unsigned u; } x; x.f = f;
    unsigned r = x.u + 0x7fff + ((x.u >> 16) & 1);   // RNE
    return (unsigned short)(r >> 16);
}
__device__ __forceinline__ float bf2f(unsigned short u){
    union { unsigned u; float f; } x; x.u = (unsigned)u << 16; return x.f;
}

// ---------- preprocessing ----------
__global__ void k_init(int* deg, float* lsum, int* cursor, int n){
    int i = blockIdx.x*blockDim.x + threadIdx.x;
    if (i < n){ deg[i]=0; lsum[i]=0.f; cursor[i]=0; }
}

__global__ void k_count(const int* __restrict__ dst, const float* __restrict__ eattr,
                        int* deg, float* lsum, int E){
    int e = blockIdx.x*blockDim.x + threadIdx.x;
    if (e < E){
        int d = dst[e];
        atomicAdd(&deg[d], 1);
        atomicAdd(&lsum[d], eattr[e]);
    }
}

// single-block scan: offs[0]=0, offs[i+1]=sum deg[0..i]
__global__ void k_scan(const int* __restrict__ deg, int* __restrict__ offs, int n){
    __shared__ int wsum[16];
    __shared__ int carry;
    int tid = threadIdx.x;            // 1024 threads
    if (tid == 0) carry = 0;
    __syncthreads();
    int lane = tid & 63, wid = tid >> 6;
    for (int base = 0; base < n; base += 1024){
        int i = base + tid;
        int x = (i < n) ? deg[i] : 0;
        #pragma unroll
        for (int o = 1; o < 64; o <<= 1){
            int y = __shfl_up(x, o);
            if (lane >= o) x += y;
        }
        if (lane == 63) wsum[wid] = x;
        __syncthreads();
        if (tid == 0){
            int run = 0;
            for (int w = 0; w < 16; w++){ run += wsum[w]; wsum[w] = run; }
        }
        __syncthreads();
        int pre = (wid > 0 ? wsum[wid-1] : 0) + carry;
        int incl = x + pre;
        if (i < n) offs[i+1] = incl;
        __syncthreads();
        if (tid == 1023) carry = incl;
        __syncthreads();
    }
    if (tid == 0) offs[0] = 0;
}

__global__ void k_loopattr(const int* deg, const float* lsum, float* lattr, int n){
    int i = blockIdx.x*blockDim.x + threadIdx.x;
    if (i < n) lattr[i] = lsum[i] / fmaxf((float)deg[i], 1.0f);
}

__global__ void k_scatter(const int* __restrict__ src, const int* __restrict__ dst,
                          const float* __restrict__ eattr, const int* __restrict__ offs,
                          int* cursor, int2* csr, int E){
    int e = blockIdx.x*blockDim.x + threadIdx.x;
    if (e < E){
        int d = dst[e];
        int pos = offs[d] + atomicAdd(&cursor[d], 1);
        int2 pk; pk.x = src[e]; pk.y = __float_as_int(eattr[e]);
        csr[pos] = pk;
    }
}

// ---------- fp32 dual GEMM (layer 0 only, din=3), bf16 outputs ----------
__global__ __launch_bounds__(256) void k_dualgemm(
        const float* __restrict__ h, int din,
        const float* __restrict__ Wl, const float* __restrict__ bl,
        const float* __restrict__ Wr, const float* __restrict__ br,
        unsigned short* __restrict__ xl, unsigned short* __restrict__ xr, int n)
{
    const int ROWS = 16;
    __shared__ float hs[ROWS * HCDIM];
    int row0 = blockIdx.x * ROWS;
    int j = threadIdx.x;

    for (int idx = threadIdx.x; idx < ROWS*din; idx += 256){
        int r = idx / din, k = idx - r*din;
        int row = row0 + r;
        hs[r*din + k] = (row < n) ? h[(size_t)row*din + k] : 0.f;
    }
    __syncthreads();

    float accl[ROWS], accr[ROWS];
    float blj = bl[j], brj = br[j];
    #pragma unroll
    for (int r = 0; r < ROWS; r++){ accl[r] = blj; accr[r] = brj; }

    for (int k = 0; k < din; k++){
        float wl = Wl[k*HCDIM + j], wr = Wr[k*HCDIM + j];
        #pragma unroll
        for (int r = 0; r < ROWS; r++){
            float hv = hs[r*din + k];
            accl[r] += hv*wl;
            accr[r] += hv*wr;
        }
    }
    #pragma unroll
    for (int r = 0; r < ROWS; r++){
        int row = row0 + r;
        if (row < n){
            xl[(size_t)row*HCDIM + j] = f2bf(accl[r]);
            xr[(size_t)row*HCDIM + j] = f2bf(accr[r]);
        }
    }
}

// ---------- weight convert+transpose: Wt[n][k] = bf16(W{l,r}[k][n]) ----------
__global__ __launch_bounds__(256) void k_cvtw(const float* __restrict__ Wl,
                                              const float* __restrict__ Wr,
                                              unsigned short* __restrict__ Wt){
    int idx = blockIdx.x*256 + threadIdx.x;   // idx = nout*256 + k, nout in [0,512)
    int nout = idx >> 8, k = idx & 255;
    float v = (nout < 256) ? Wl[k*HCDIM + nout] : Wr[k*HCDIM + (nout - 256)];
    Wt[idx] = f2bf(v);
}

// ---------- bf16 MFMA GEMM: [xl | xr] = h @ [Wl | Wr] + [bl | br] ----------
// A = h [n][256] bf16 ; B = Wt [512][256] bf16 n-major; bf16 outputs
#define BM 128
#define BN 128
#define BK 32
#define LDK 40   // padded LDS stride (bf16 elems)

typedef __attribute__((ext_vector_type(8))) short bf16x8;
typedef __attribute__((ext_vector_type(4))) float f32x4;

__global__ __launch_bounds__(256) void k_mfma_gemm(
        const unsigned short* __restrict__ h,
        const unsigned short* __restrict__ Wt,
        const float* __restrict__ bl, const float* __restrict__ br,
        unsigned short* __restrict__ xl, unsigned short* __restrict__ xr, int n)
{
    __shared__ unsigned short As[BM*LDK];
    __shared__ unsigned short Bs[BN*LDK];
    int tid = threadIdx.x;
    int row0 = blockIdx.x * BM;
    int col0 = blockIdx.y * BN;      // 0,128,256,384 over [Wl|Wr]

    int l = tid & 63, w = tid >> 6;
    int wm = (w >> 1) * 64, wn = (w & 1) * 64;

    f32x4 acc[4][4] = {};

    int srow = tid >> 1;
    int skoff = (tid & 1) * 16;

    for (int kt = 0; kt < 8; ++kt){
        int kb = kt * BK;
        uint4 av0, av1;
        int grow = row0 + srow;
        if (grow < n){
            const uint4* ap = reinterpret_cast<const uint4*>(h + (size_t)grow*HCDIM + kb + skoff);
            av0 = ap[0]; av1 = ap[1];
        } else {
            av0.x=av0.y=av0.z=av0.w=0u; av1 = av0;
        }
        const uint4* bp = reinterpret_cast<const uint4*>(Wt + (size_t)(col0+srow)*HCDIM + kb + skoff);
        uint4 bv0 = bp[0], bv1 = bp[1];

        __syncthreads();   // previous iteration's LDS reads complete

        *reinterpret_cast<uint4*>(&As[srow*LDK + skoff])     = av0;
        *reinterpret_cast<uint4*>(&As[srow*LDK + skoff + 8]) = av1;
        *reinterpret_cast<uint4*>(&Bs[srow*LDK + skoff])     = bv0;
        *reinterpret_cast<uint4*>(&Bs[srow*LDK + skoff + 8]) = bv1;

        __syncthreads();

        bf16x8 af[4], bfr[4];
        #pragma unroll
        for (int m = 0; m < 4; m++)
            af[m] = *reinterpret_cast<const bf16x8*>(&As[(wm + m*16 + (l & 15))*LDK + ((l >> 4)*8)]);
        #pragma unroll
        for (int nn = 0; nn < 4; nn++)
            bfr[nn] = *reinterpret_cast<const bf16x8*>(&Bs[(wn + nn*16 + (l & 15))*LDK + ((l >> 4)*8)]);
        #pragma unroll
        for (int m = 0; m < 4; m++)
            #pragma unroll
            for (int nn = 0; nn < 4; nn++)
                acc[m][nn] = __builtin_amdgcn_mfma_f32_16x16x32_bf16(af[m], bfr[nn], acc[m][nn], 0, 0, 0);
    }

    unsigned short* dstp; const float* biasp; int cbase;
    if (col0 < 256){ dstp = xl; biasp = bl; cbase = col0; }
    else           { dstp = xr; biasp = br; cbase = col0 - 256; }

    #pragma unroll
    for (int nn = 0; nn < 4; nn++){
        int gc = cbase + wn + nn*16 + (l & 15);
        float bb = biasp[gc];
        #pragma unroll
        for (int m = 0; m < 4; m++){
            int r0 = row0 + wm + m*16 + ((l >> 4) * 4);
            #pragma unroll
            for (int v = 0; v < 4; v++){
                int rr = r0 + v;
                if (rr < n) dstp[(size_t)rr*HCDIM + gc] = f2bf(acc[m][nn][v] + bb);
            }
        }
    }
}

// ---------- fused GATv2 edge kernel: TWO waves per dst node (even/odd edges) ----------
// defer-max online softmax: fast path skips rescale unless logit max grows >20
// (wave-uniform __any branch; first edge always takes exact slow path).
__global__ __launch_bounds__(256) void k_gat(
        const unsigned short* __restrict__ xl, const unsigned short* __restrict__ xr,
        const int2* __restrict__ csr,
        const int* __restrict__ offs, const float* __restrict__ lattr,
        const float* __restrict__ We, const float* __restrict__ att,
        const float* __restrict__ bias,
        unsigned short* __restrict__ hout_bf, float* __restrict__ hout_f,
        int n, int concat)
{
    __shared__ float smg[4][64][6];
    int wid  = threadIdx.x >> 6;     // 0..3
    int lane = threadIdx.x & 63;
    int pair = wid >> 1;             // node slot in block
    int half = wid & 1;              // 0: even csr positions + self loop; 1: odd
    int v = blockIdx.x*2 + pair;
    bool valid = (v < n);

    const int cb = lane*4;           // head=lane/8, ch=(lane%8)*4
    float4 We4  = ld4(We + cb);
    float4 att4 = ld4(att + cb);
    float xrx=0,xry=0,xrz=0,xrw=0;
    int pbeg=0, pend=0;
    float la = 0.f;
    if (valid){
        ushort4 xr4u = *reinterpret_cast<const ushort4*>(xr + (size_t)v*HCDIM + cb);
        xrx = bf2f(xr4u.x); xry = bf2f(xr4u.y); xrz = bf2f(xr4u.z); xrw = bf2f(xr4u.w);
        pbeg = offs[v]; pend = offs[v+1];
        la = lattr[v];
    }

    float mh = -INFINITY, s = 0.f;
    float ax = 0.f, ay = 0.f, az = 0.f, aw = 0.f;

    auto edge_step = [&](ushort4 xu4, float ea){
        float xux = bf2f(xu4.x), xuy = bf2f(xu4.y), xuz = bf2f(xu4.z), xuw = bf2f(xu4.w);
        float tx = xux + fmaf(ea, We4.x, xrx);
        float ty = xuy + fmaf(ea, We4.y, xry);
        float tz = xuz + fmaf(ea, We4.z, xrz);
        float tw = xuw + fmaf(ea, We4.w, xrw);
        tx = fmaxf(tx, NEG*tx);          // leaky relu, slope<1
        ty = fmaxf(ty, NEG*ty);
        tz = fmaxf(tz, NEG*tz);
        tw = fmaxf(tw, NEG*tw);
        float part = tx*att4.x + ty*att4.y + tz*att4.z + tw*att4.w;
        part += __shfl_xor(part, 1);
        part += __shfl_xor(part, 2);
        part += __shfl_xor(part, 4);     // logit uniform within head's 8 lanes
        float d = part - mh;             // +inf on first edge
        if (__any(d > 20.f)){            // slow path: exact online rescale
            float nm = fmaxf(mh, part);
            float sc = __expf(mh - nm);  // exp(-inf)=0 on first edge
            float w  = __expf(part - nm);
            s  = s*sc + w;
            ax = ax*sc + w*xux;
            ay = ay*sc + w*xuy;
            az = az*sc + w*xuz;
            aw = aw*sc + w*xuw;
            mh = nm;
        } else {                          // fast path: deferred max
            float w = __expf(d);
            s += w;
            ax = fmaf(w, xux, ax);
            ay = fmaf(w, xuy, ay);
            az = fmaf(w, xuz, az);
            aw = fmaf(w, xuw, aw);
        }
    };

    if (half == 0 && valid){
        ushort4 xv4 = *reinterpret_cast<const ushort4*>(xl + (size_t)v*HCDIM + cb);
        edge_step(xv4, la);            // self loop
    }

    // pipelined stride-2 edge loop: eA = current entry, eB = next entry (dist 2),
    // xuA = current gather (dist 1)
    int p = pbeg + half;
    int2 eA, eB; ushort4 xuA;
    if (p < pend){
        eA = csr[p];
        xuA = *reinterpret_cast<const ushort4*>(xl + ((size_t)eA.x << 8) + cb);
        if (p + 2 < pend) eB = csr[p + 2];
    }
    for (; p < pend; p += 2){
        ushort4 cur = xuA;
        float ea = __int_as_float(eA.y);
        if (p + 2 < pend){
            xuA = *reinterpret_cast<const ushort4*>(xl + ((size_t)eB.x << 8) + cb);
            eA = eB;
            if (p + 4 < pend) eB = csr[p + 4];
        }
        edge_step(cur, ea);
    }

    // merge the two halves' online-softmax states
    smg[wid][lane][0] = mh; smg[wid][lane][1] = s;
    smg[wid][lane][2] = ax; smg[wid][lane][3] = ay;
    smg[wid][lane][4] = az; smg[wid][lane][5] = aw;
    __syncthreads();
    if (half != 0 || !valid) return;

    float m2  = smg[wid+1][lane][0];
    float s2  = smg[wid+1][lane][1];
    float a2x = smg[wid+1][lane][2];
    float a2y = smg[wid+1][lane][3];
    float a2z = smg[wid+1][lane][4];
    float a2w = smg[wid+1][lane][5];
    float M  = fmaxf(mh, m2);          // mh finite (self loop) => M finite
    float c1 = __expf(mh - M);
    float c2 = __expf(m2 - M);         // exp(-inf)=0 when half1 empty
    s  = s*c1 + s2*c2;
    ax = ax*c1 + a2x*c2;
    ay = ay*c1 + a2y*c2;
    az = az*c1 + a2z*c2;
    aw = aw*c1 + a2w*c2;

    float inv = 1.f / s;
    if (concat){
        float4 b4 = ld4(bias + cb);
        ushort4 o;
        o.x = f2bf(fmaxf(ax*inv + b4.x, 0.f));
        o.y = f2bf(fmaxf(ay*inv + b4.y, 0.f));
        o.z = f2bf(fmaxf(az*inv + b4.z, 0.f));
        o.w = f2bf(fmaxf(aw*inv + b4.w, 0.f));
        *reinterpret_cast<ushort4*>(hout_bf + (size_t)v*HCDIM + cb) = o;
    } else {
        float ox = ax*inv, oy = ay*inv, oz = az*inv, ow = aw*inv;
        #pragma unroll
        for (int o = 8; o < 64; o <<= 1){
            ox += __shfl_xor(ox, o); oy += __shfl_xor(oy, o);
            oz += __shfl_xor(oz, o); ow += __shfl_xor(ow, o);
        }
        int c0 = (lane & 7)*4;
        float4 b4 = ld4(bias + c0);
        ox = fmaxf(ox*0.125f + b4.x, 0.f);
        oy = fmaxf(oy*0.125f + b4.y, 0.f);
        oz = fmaxf(oz*0.125f + b4.z, 0.f);
        ow = fmaxf(ow*0.125f + b4.w, 0.f);
        if (lane < 8) st4(hout_f + (size_t)v*CH + c0, ox, oy, oz, ow);
    }
}

// ---------- node head: 32 threads per node (N only — cheap) ----------
__global__ __launch_bounds__(256) void k_head(
        const float* __restrict__ hf,
        const float* __restrict__ W1, const float* __restrict__ b1,
        const float* __restrict__ W2, const float* __restrict__ b2,
        float* __restrict__ out, int count)
{
    __shared__ float sh[8][CH];
    int g = threadIdx.x >> 5;
    int t = threadIdx.x & 31;
    int i = blockIdx.x*8 + g;
    float hv = (i < count) ? hf[(size_t)i*CH + t] : 0.f;
    sh[g][t] = hv;
    __syncthreads();
    float z = b1[t];
    #pragma unroll
    for (int k = 0; k < CH; k++) z += sh[g][k] * W1[k*CH + t];
    z = fmaxf(z, 0.f);
    float r0 = z * W2[t*2 + 0];
    float r1 = z * W2[t*2 + 1];
    #pragma unroll
    for (int o = 1; o < 32; o <<= 1){
        r0 += __shfl_xor(r0, o);
        r1 += __shfl_xor(r1, o);
    }
    if (t == 0 && i < count){
        float z0 = r0 + b2[0], z1 = r1 + b2[1];
        float mm = fmaxf(z0, z1);
        float lse = mm + __logf(__expf(z0 - mm) + __expf(z1 - mm));
        out[(size_t)i*2 + 0] = z0 - lse;
        out[(size_t)i*2 + 1] = z1 - lse;
    }
}

// ---------- per-node P = h @ W1 (no bias) for the edge head ----------
__global__ __launch_bounds__(256) void k_mlp1(
        const float* __restrict__ hf, const float* __restrict__ W1,
        float* __restrict__ P, int count)
{
    __shared__ float sh[8][CH];
    int g = threadIdx.x >> 5;
    int t = threadIdx.x & 31;
    int i = blockIdx.x*8 + g;
    sh[g][t] = (i < count) ? hf[(size_t)i*CH + t] : 0.f;
    __syncthreads();
    float z = 0.f;
    #pragma unroll
    for (int k = 0; k < CH; k++) z += sh[g][k] * W1[k*CH + t];
    if (i < count) P[(size_t)i*CH + t] = z;
}

// ---------- edge head finisher: 8 lanes per edge ----------
__global__ __launch_bounds__(256) void k_edgefin(
        const float* __restrict__ P,
        const int* __restrict__ src, const int* __restrict__ dst,
        const float* __restrict__ b1, const float* __restrict__ W2,
        const float* __restrict__ b2, float* __restrict__ out, int E)
{
    int gt = blockIdx.x*256 + threadIdx.x;
    int e = gt >> 3, sub = gt & 7;
    if (e >= E) return;
    int s = src[e], d = dst[e];
    int c0 = sub*4;
    float4 ps = ld4(P + (size_t)s*CH + c0);
    float4 pd = ld4(P + (size_t)d*CH + c0);
    float4 bb = ld4(b1 + c0);
    float zx = fmaxf(ps.x + pd.x + bb.x, 0.f);
    float zy = fmaxf(ps.y + pd.y + bb.y, 0.f);
    float zz = fmaxf(ps.z + pd.z + bb.z, 0.f);
    float zw = fmaxf(ps.w + pd.w + bb.w, 0.f);
    float r0 = zx*W2[(c0+0)*2] + zy*W2[(c0+1)*2] + zz*W2[(c0+2)*2] + zw*W2[(c0+3)*2];
    float r1 = zx*W2[(c0+0)*2+1] + zy*W2[(c0+1)*2+1] + zz*W2[(c0+2)*2+1] + zw*W2[(c0+3)*2+1];
    #pragma unroll
    for (int o = 1; o < 8; o <<= 1){
        r0 += __shfl_xor(r0, o);
        r1 += __shfl_xor(r1, o);
    }
    if (sub == 0){
        float z0 = r0 + b2[0], z1 = r1 + b2[1];
        float mm = fmaxf(z0, z1);
        float lse = mm + __logf(__expf(z0 - mm) + __expf(z1 - mm));
        float2 o2; o2.x = z0 - lse; o2.y = z1 - lse;
        *reinterpret_cast<float2*>(out + (size_t)e*2) = o2;
    }
}

extern "C" void kernel_launch(void* const* d_in, const int* in_sizes, int n_in,
                              void* d_out, int out_size, void* d_ws, size_t ws_size,
                              hipStream_t stream)
{
    const float* x     = (const float*)d_in[0];
    const int*   ei    = (const int*)d_in[1];
    const float* eattr = (const float*)d_in[2];
    int N = in_sizes[0] / 3;
    int E = in_sizes[2];
    const int* src0 = ei;
    const int* dst0 = ei + E;

    const float *Wl[3], *bl[3], *Wr[3], *br[3], *We[3], *att[3], *bias[3];
    for (int l = 0; l < 3; l++){
        int b = 3 + l*7;
        Wl[l]   = (const float*)d_in[b+0];
        bl[l]   = (const float*)d_in[b+1];
        Wr[l]   = (const float*)d_in[b+2];
        br[l]   = (const float*)d_in[b+3];
        We[l]   = (const float*)d_in[b+4];
        att[l]  = (const float*)d_in[b+5];
        bias[l] = (const float*)d_in[b+6];
    }
    const float* nhW1 = (const float*)d_in[24];
    const float* nhb1 = (const float*)d_in[25];
    const float* nhW2 = (const float*)d_in[26];
    const float* nhb2 = (const float*)d_in[27];
    const float* ehW1 = (const float*)d_in[28];
    const float* ehb1 = (const float*)d_in[29];
    const float* ehW2 = (const float*)d_in[30];
    const float* ehb2 = (const float*)d_in[31];

    char* ws = (char*)d_ws;
    auto alloc = [&](size_t bytes) -> char* {
        char* p = ws;
        ws += (bytes + 255) & ~(size_t)255;
        return p;
    };
    unsigned short* Hb       = (unsigned short*)alloc((size_t)N*HCDIM*2);  // layers 0/1 output
    float* H0f               = (float*)alloc((size_t)N*CH*4);              // layer 2 output
    unsigned short* XL       = (unsigned short*)alloc((size_t)N*HCDIM*2);
    unsigned short* XR       = (unsigned short*)alloc((size_t)N*HCDIM*2);
    int*   deg      = (int*)alloc((size_t)N*4);
    float* lsum     = (float*)alloc((size_t)N*4);
    float* lattr    = (float*)alloc((size_t)N*4);
    int*   offs     = (int*)alloc((size_t)(N+1)*4);
    int*   cursor   = (int*)alloc((size_t)N*4);
    int2*  csr      = (int2*)alloc((size_t)E*8);
    unsigned short* Wt = (unsigned short*)alloc((size_t)512*HCDIM*2);
    float* Pe       = (float*)alloc((size_t)N*CH*4);

    // preprocessing
    k_init<<<(N+255)/256, 256, 0, stream>>>(deg, lsum, cursor, N);
    k_count<<<(E+255)/256, 256, 0, stream>>>(dst0, eattr, deg, lsum, E);
    k_scan<<<1, 1024, 0, stream>>>(deg, offs, N);
    k_loopattr<<<(N+255)/256, 256, 0, stream>>>(deg, lsum, lattr, N);
    k_scatter<<<(E+255)/256, 256, 0, stream>>>(src0, dst0, eattr, offs, cursor, csr, E);

    int gat_grid  = (N + 1) / 2;     // 2 nodes per block, 2 waves per node
    dim3 mfma_grid((N + BM - 1) / BM, 4);

    // layer 0 (din=3, fp32 vector GEMM -> bf16 xl/xr)
    k_dualgemm<<<(N+15)/16, 256, 0, stream>>>(x, 3, Wl[0], bl[0], Wr[0], br[0], XL, XR, N);
    k_gat<<<gat_grid, 256, 0, stream>>>(XL, XR, csr, offs, lattr,
                                        We[0], att[0], bias[0], Hb, nullptr, N, 1);
    // layer 1 (din=256, bf16 MFMA)
    k_cvtw<<<512, 256, 0, stream>>>(Wl[1], Wr[1], Wt);
    k_mfma_gemm<<<mfma_grid, 256, 0, stream>>>(Hb, Wt, bl[1], br[1], XL, XR, N);
    k_gat<<<gat_grid, 256, 0, stream>>>(XL, XR, csr, offs, lattr,
                                        We[1], att[1], bias[1], Hb, nullptr, N, 1);
    // layer 2 (din=256, bf16 MFMA, concat=false -> f32 N x 32)
    k_cvtw<<<512, 256, 0, stream>>>(Wl[2], Wr[2], Wt);
    k_mfma_gemm<<<mfma_grid, 256, 0, stream>>>(Hb, Wt, bl[2], br[2], XL, XR, N);
    k_gat<<<gat_grid, 256, 0, stream>>>(XL, XR, csr, offs, lattr,
                                        We[2], att[2], bias[2], nullptr, H0f, N, 0);

    // node head (per-node, cheap)
    float* out_node = (float*)d_out;
    float* out_edge = out_node + (size_t)N*2;
    k_head<<<(N+7)/8, 256, 0, stream>>>(H0f, nhW1, nhb1, nhW2, nhb2, out_node, N);

    // edge head: P = H0f @ ehW1 per node, then tiny per-edge finisher
    k_mlp1<<<(N+7)/8, 256, 0, stream>>>(H0f, ehW1, Pe, N);
    k_edgefin<<<((size_t)E*8 + 255)/256, 256, 0, stream>>>(Pe, src0, dst0,
                                                           ehb1, ehW2, ehb2, out_edge, E);
}